// Round 2
// baseline (44968.838 us; speedup 1.0000x reference)
//
#include <hip/hip_runtime.h>
#include <hip/hip_bf16.h>

typedef __hip_bfloat16 bf16;

__device__ __forceinline__ float b2f(bf16 v) { return __bfloat162float(v); }
__device__ __forceinline__ bf16 f2b(float v) { return __float2bfloat16(v); }
__device__ __forceinline__ float bfbits2f(unsigned short u) {
    return __uint_as_float((unsigned int)u << 16);
}

__device__ __forceinline__ void atomicAddF(float* p, float v) {
    unsafeAtomicAdd(p, v);   // hardware global_atomic_add_f32 on gfx950
}

// out[i,j] = sum_k x[i,k]*W[k,j] + b[j]   (x,W,b f32 -> out bf16), no relu
// Register-tiled: each wave computes 4 rows; k unrolled x4 with float4 LDS reads.
template<int F>
__global__ void proj_kernel(const float* __restrict__ x, const float* __restrict__ W,
                            const float* __restrict__ b, bf16* __restrict__ out, int n) {
    __shared__ float sW[F][64];
    __shared__ float sb[64];
    __shared__ float sx[16][F];
    int tid = threadIdx.x;
    for (int idx = tid; idx < F * 64; idx += 256) sW[idx >> 6][idx & 63] = W[idx];
    if (tid < 64) sb[tid] = b[tid];
    int base = blockIdx.x * 64;
    int w = tid >> 6, j = tid & 63;
    int lw = w * 4;
    for (int g = 0; g < 4; ++g) {
        int row0 = base + g * 16;
        __syncthreads();   // covers W-load (g=0) / prior compute reads of sx (g>0)
        // stage 16 rows of x as float4 (coalesced)
        for (int idx = tid; idx < 4 * F; idx += 256) {   // 16*F/4 float4s
            int rr = idx / (F / 4), c4 = idx % (F / 4);
            int row = row0 + rr;
            float4 v = (row < n) ? ((const float4*)x)[(size_t)row * (F / 4) + c4]
                                 : make_float4(0.f, 0.f, 0.f, 0.f);
            *(float4*)&sx[rr][c4 * 4] = v;
        }
        __syncthreads();
        float acc[4];
#pragma unroll
        for (int rr = 0; rr < 4; ++rr) acc[rr] = sb[j];
#pragma unroll
        for (int k = 0; k < F; k += 4) {
            float w0 = sW[k][j], w1 = sW[k + 1][j], w2 = sW[k + 2][j], w3 = sW[k + 3][j];
#pragma unroll
            for (int rr = 0; rr < 4; ++rr) {
                float4 m = *(const float4*)&sx[lw + rr][k];
                acc[rr] += m.x * w0 + m.y * w1 + m.z * w2 + m.w * w3;
            }
        }
#pragma unroll
        for (int rr = 0; rr < 4; ++rr) {
            int row = row0 + lw + rr;
            if (row < n) out[(size_t)row * 64 + j] = f2b(acc[rr]);
        }
    }
}

// agg[dst[e], :] += h[src[e], :]   (one wave per edge, lane = feature)
// cnt != nullptr: also accumulate degree (fused count, conv1 only)
__global__ void agg_kernel(const bf16* __restrict__ h, const int* __restrict__ src,
                           const int* __restrict__ dst, float* __restrict__ agg,
                           float* __restrict__ cnt, int ne) {
    int e = blockIdx.x * 4 + (threadIdx.x >> 6);
    if (e >= ne) return;
    int lane = threadIdx.x & 63;
    int s = src[e], d = dst[e];
    float v = b2f(h[(size_t)s * 64 + lane]);
    atomicAddF(&agg[(size_t)d * 64 + lane], v);
    if (cnt && lane == 0) atomicAddF(&cnt[d], 1.0f);
}

// out[i,j] = relu( (agg[i,:]/max(cnt_i,1)) . Wl[:,j] + bl[j] + xd[i,:] . Wr[:,j] )
// Register-tiled: wave w owns rows lw..lw+3 of each 16-row group; k unrolled x4
// with float4 (b128) LDS reads -> ~4x fewer LDS instructions per FLOP.
// In-place outb==xd is safe (group staged to LDS, synced, then overwritten).
// HEAD=true: fused logits = relu(t2 @ Wh1 + bh1) @ Wh2 + bh2 (t2 re-staged
// wave-locally in sm; per-wave LDS program order makes this safe).
template<bool HEAD>
__global__ void sage_out_kernel(const float* __restrict__ agg, const float* __restrict__ cnt,
                                const bf16* __restrict__ xd,
                                const float* __restrict__ Wl, const float* __restrict__ bl,
                                const float* __restrict__ Wr,
                                float* __restrict__ outf, bf16* __restrict__ outb,
                                const float* __restrict__ Wh1, const float* __restrict__ bh1,
                                const float* __restrict__ Wh2, const float* __restrict__ bh2,
                                float* __restrict__ logits, int n) {
    __shared__ float sWl[64][64];
    __shared__ float sWr[64][64];
    __shared__ float sW1[HEAD ? 64 : 1][64];
    __shared__ float sbl[64];
    __shared__ float sb1[HEAD ? 64 : 1];
    __shared__ float sW2[HEAD ? 128 : 2];
    __shared__ float sb2[2];
    __shared__ float sm[16][64];
    __shared__ float sx[16][64];
    __shared__ float sc[16];
    int tid = threadIdx.x;
    for (int idx = tid; idx < 4096; idx += 256) {
        sWl[idx >> 6][idx & 63] = Wl[idx];
        sWr[idx >> 6][idx & 63] = Wr[idx];
        if (HEAD) sW1[idx >> 6][idx & 63] = Wh1[idx];
    }
    if (tid < 64) sbl[tid] = bl[tid];
    if (HEAD) {
        if (tid >= 64 && tid < 128) sb1[tid - 64] = bh1[tid - 64];
        if (tid >= 128 && tid < 256) sW2[tid - 128] = Wh2[tid - 128];
        if (tid < 2) sb2[tid] = bh2[tid];
    }
    int base = blockIdx.x * 64;
    int w = tid >> 6, j = tid & 63;
    int lw = w * 4;
    for (int g = 0; g < 4; ++g) {
        int row0 = base + g * 16;
        __syncthreads();   // weights (g=0) / prior-group LDS reuse (g>0)
        {
            // stage 16 rows: agg as float4 (1/thread), xd as 4xbf16 (1/thread)
            int rr = tid >> 4, c4 = tid & 15;
            int row = row0 + rr;
            float4 a = make_float4(0.f, 0.f, 0.f, 0.f);
            float4 xv = make_float4(0.f, 0.f, 0.f, 0.f);
            if (row < n) {
                a = ((const float4*)agg)[(size_t)row * 16 + c4];
                ushort4 u = ((const ushort4*)xd)[(size_t)row * 16 + c4];
                xv.x = bfbits2f(u.x); xv.y = bfbits2f(u.y);
                xv.z = bfbits2f(u.z); xv.w = bfbits2f(u.w);
            }
            *(float4*)&sm[rr][c4 * 4] = a;
            *(float4*)&sx[rr][c4 * 4] = xv;
            if (tid < 16) sc[tid] = (row0 + tid < n) ? cnt[row0 + tid] : 1.f;
        }
        __syncthreads();
        float accl[4], accr[4];
#pragma unroll
        for (int rr = 0; rr < 4; ++rr) { accl[rr] = 0.f; accr[rr] = 0.f; }
#pragma unroll
        for (int k = 0; k < 64; k += 4) {
            float wl0 = sWl[k][j], wl1 = sWl[k + 1][j], wl2 = sWl[k + 2][j], wl3 = sWl[k + 3][j];
            float wr0 = sWr[k][j], wr1 = sWr[k + 1][j], wr2 = sWr[k + 2][j], wr3 = sWr[k + 3][j];
#pragma unroll
            for (int rr = 0; rr < 4; ++rr) {
                float4 m = *(const float4*)&sm[lw + rr][k];
                float4 xv = *(const float4*)&sx[lw + rr][k];
                accl[rr] += m.x * wl0 + m.y * wl1 + m.z * wl2 + m.w * wl3;
                accr[rr] += xv.x * wr0 + xv.y * wr1 + xv.z * wr2 + xv.w * wr3;
            }
        }
        float v[4];
#pragma unroll
        for (int rr = 0; rr < 4; ++rr) {
            float inv = 1.f / fmaxf(sc[lw + rr], 1.f);
            v[rr] = fmaxf(accl[rr] * inv + sbl[j] + accr[rr], 0.f);
            int row = row0 + lw + rr;
            if (row < n) {
                if (outf) outf[(size_t)row * 64 + j] = v[rr];
                if (outb) outb[(size_t)row * 64 + j] = f2b(v[rr]);
            }
        }
        if (HEAD) {
            // Wave-local t2 staging: wave w exclusively owns sm rows lw..lw+3;
            // per-wave LDS ops retire in program order, so writes below are
            // ordered before the reads in the k-loop (same wave only reads them).
#pragma unroll
            for (int rr = 0; rr < 4; ++rr) sm[lw + rr][j] = v[rr];
            float acch[4];
#pragma unroll
            for (int rr = 0; rr < 4; ++rr) acch[rr] = sb1[j];
#pragma unroll
            for (int k = 0; k < 64; k += 4) {
                float h0 = sW1[k][j], h1 = sW1[k + 1][j], h2 = sW1[k + 2][j], h3 = sW1[k + 3][j];
#pragma unroll
                for (int rr = 0; rr < 4; ++rr) {
                    float4 m = *(const float4*)&sm[lw + rr][k];
                    acch[rr] += m.x * h0 + m.y * h1 + m.z * h2 + m.w * h3;
                }
            }
#pragma unroll
            for (int rr = 0; rr < 4; ++rr) {
                float hid = fmaxf(acch[rr], 0.f);
                float p0 = hid * sW2[j * 2 + 0];
                float p1 = hid * sW2[j * 2 + 1];
#pragma unroll
                for (int off = 32; off; off >>= 1) {
                    p0 += __shfl_down(p0, off);
                    p1 += __shfl_down(p1, off);
                }
                int row = row0 + lw + rr;
                if (j == 0 && row < n) {
                    logits[(size_t)row * 2 + 0] = p0 + sb2[0];
                    logits[(size_t)row * 2 + 1] = p1 + sb2[1];
                }
            }
        }
    }
}

extern "C" void kernel_launch(void* const* d_in, const int* in_sizes, int n_in,
                              void* d_out, int out_size, void* d_ws, size_t ws_size,
                              hipStream_t stream) {
    const float* x_tx   = (const float*)d_in[0];
    const float* x_w    = (const float*)d_in[1];
    const int*   src_tw = (const int*)d_in[2];
    const int*   dst_tw = (const int*)d_in[3];
    const int*   src_wt = (const int*)d_in[4];
    const int*   dst_wt = (const int*)d_in[5];
    const float* Win_tx = (const float*)d_in[6];
    const float* bin_tx = (const float*)d_in[7];
    const float* Win_w  = (const float*)d_in[8];
    const float* bin_w  = (const float*)d_in[9];
    const float* Wl1_tw = (const float*)d_in[10];
    const float* bl1_tw = (const float*)d_in[11];
    const float* Wr1_tw = (const float*)d_in[12];
    const float* Wl1_wt = (const float*)d_in[13];
    const float* bl1_wt = (const float*)d_in[14];
    const float* Wr1_wt = (const float*)d_in[15];
    const float* Wl2_tw = (const float*)d_in[16];
    const float* bl2_tw = (const float*)d_in[17];
    const float* Wr2_tw = (const float*)d_in[18];
    const float* Wl2_wt = (const float*)d_in[19];
    const float* bl2_wt = (const float*)d_in[20];
    const float* Wr2_wt = (const float*)d_in[21];
    const float* Wh1    = (const float*)d_in[22];
    const float* bh1    = (const float*)d_in[23];
    const float* Wh2    = (const float*)d_in[24];
    const float* bh2    = (const float*)d_in[25];

    const int n_tx  = in_sizes[0] / 64;
    const int n_w   = in_sizes[1] / 32;
    const int ne_tw = in_sizes[2];
    const int ne_wt = in_sizes[4];

    // workspace layout (~485 MB) — aggE and aggC are SEPARATE (both alive in conv1)
    float* aggE   = (float*)d_ws;                         // n_tx*64 f32 : agg into tx
    float* aggC   = aggE + (size_t)n_tx * 64;             // n_w *64 f32 : agg into wallets
    bf16*  A      = (bf16*)(aggC + (size_t)n_w * 64);     // n_tx*64 bf16: h_tx -> t1 (in-place)
    bf16*  B      = A + (size_t)n_tx * 64;                // n_w *64 bf16: h_w  -> w1 (in-place)
    float* cnt_w  = (float*)(B + (size_t)n_w * 64);       // n_w
    float* cnt_tx = cnt_w + n_w;                          // n_tx

    float* out_logits = (float*)d_out;
    float* out_t2 = out_logits + (size_t)n_tx * 2;
    float* out_w2 = out_t2 + (size_t)n_tx * 64;

    const size_t bytes_aggw  = (size_t)n_w * 64 * sizeof(float);
    const size_t bytes_aggtx = (size_t)n_tx * 64 * sizeof(float);

    dim3 blk(256);
    int grid_proj_tx = (n_tx + 63) / 64;
    int grid_proj_w  = (n_w + 63) / 64;
    int grid_agg_tw  = (ne_tw + 3) / 4;
    int grid_agg_wt  = (ne_wt + 3) / 4;

    // zero counters + agg buffers, project inputs
    hipMemsetAsync(cnt_w, 0, (size_t)n_w * sizeof(float), stream);
    hipMemsetAsync(cnt_tx, 0, (size_t)n_tx * sizeof(float), stream);
    hipMemsetAsync(aggE, 0, bytes_aggtx, stream);
    hipMemsetAsync(aggC, 0, bytes_aggw, stream);
    proj_kernel<64><<<grid_proj_tx, blk, 0, stream>>>(x_tx, Win_tx, bin_tx, A, n_tx);
    proj_kernel<32><<<grid_proj_w, blk, 0, stream>>>(x_w, Win_w, bin_w, B, n_w);

    // conv1: BOTH aggregations first (fused degree count), THEN both epilogues
    agg_kernel<<<grid_agg_tw, blk, 0, stream>>>(A, src_tw, dst_tw, aggC, cnt_w, ne_tw);  // h_tx -> w
    agg_kernel<<<grid_agg_wt, blk, 0, stream>>>(B, src_wt, dst_wt, aggE, cnt_tx, ne_wt); // h_w  -> tx
    sage_out_kernel<false><<<grid_proj_w, blk, 0, stream>>>(
        aggC, cnt_w, B, Wl1_tw, bl1_tw, Wr1_tw,
        nullptr, B, nullptr, nullptr, nullptr, nullptr, nullptr, n_w);            // w1 (in-place B)
    sage_out_kernel<false><<<grid_proj_tx, blk, 0, stream>>>(
        aggE, cnt_tx, A, Wl1_wt, bl1_wt, Wr1_wt,
        nullptr, A, nullptr, nullptr, nullptr, nullptr, nullptr, n_tx);           // t1 (in-place A)

    // conv2: re-zero agg buffers, both aggregations (from t1=A, w1=B), both epilogues
    hipMemsetAsync(aggC, 0, bytes_aggw, stream);
    hipMemsetAsync(aggE, 0, bytes_aggtx, stream);
    agg_kernel<<<grid_agg_tw, blk, 0, stream>>>(A, src_tw, dst_tw, aggC, nullptr, ne_tw); // t1 -> w
    agg_kernel<<<grid_agg_wt, blk, 0, stream>>>(B, src_wt, dst_wt, aggE, nullptr, ne_wt); // w1 -> tx
    sage_out_kernel<false><<<grid_proj_w, blk, 0, stream>>>(
        aggC, cnt_w, B, Wl2_tw, bl2_tw, Wr2_tw,
        out_w2, nullptr, nullptr, nullptr, nullptr, nullptr, nullptr, n_w);       // w2 -> f32 out
    // t2 epilogue + fused head: writes out_t2 AND out_logits in one pass
    sage_out_kernel<true><<<grid_proj_tx, blk, 0, stream>>>(
        aggE, cnt_tx, A, Wl2_wt, bl2_wt, Wr2_wt,
        out_t2, nullptr, Wh1, bh1, Wh2, bh2, out_logits, n_tx);                   // t2 + logits
}

// Round 3
// 4588.601 us; speedup vs baseline: 9.8001x; 9.8001x over previous
//
#include <hip/hip_runtime.h>
#include <hip/hip_bf16.h>

typedef __hip_bfloat16 bf16;

__device__ __forceinline__ float b2f(bf16 v) { return __bfloat162float(v); }
__device__ __forceinline__ bf16 f2b(float v) { return __float2bfloat16(v); }
__device__ __forceinline__ float bfbits2f(unsigned short u) {
    return __uint_as_float((unsigned int)u << 16);
}

__device__ __forceinline__ void atomicAddF(float* p, float v) {
    unsafeAtomicAdd(p, v);   // hardware global_atomic_add_f32 on gfx950
}

// out[i,j] = sum_k x[i,k]*W[k,j] + b[j]   (x,W,b f32 -> out bf16), no relu
// Wave w owns rows lw..lw+3 of each 16-row group. All private values are NAMED
// SCALARS (no arrays -> no scratch risk); k-loop unroll bounded to 2.
template<int F>
__global__ void proj_kernel(const float* __restrict__ x, const float* __restrict__ W,
                            const float* __restrict__ b, bf16* __restrict__ out, int n) {
    __shared__ float sW[F][64];
    __shared__ float sb[64];
    __shared__ float sx[16][F];
    int tid = threadIdx.x;
    for (int idx = tid; idx < F * 16; idx += 256)          // F*64/4 float4s
        ((float4*)sW)[idx] = ((const float4*)W)[idx];
    if (tid < 64) sb[tid] = b[tid];
    int base = blockIdx.x * 64;
    int w = tid >> 6, j = tid & 63;
    int lw = w * 4;
    for (int g = 0; g < 4; ++g) {
        int row0 = base + g * 16;
        __syncthreads();   // covers W-load (g=0) / prior compute reads of sx (g>0)
        for (int idx = tid; idx < 4 * F; idx += 256) {     // 16*(F/4) float4s
            int rr = idx / (F / 4), c4 = idx - rr * (F / 4);
            int row = row0 + rr;
            float4 v = (row < n) ? ((const float4*)x)[(size_t)row * (F / 4) + c4]
                                 : make_float4(0.f, 0.f, 0.f, 0.f);
            *(float4*)&sx[rr][c4 * 4] = v;
        }
        __syncthreads();
        float a0 = sb[j], a1 = sb[j], a2 = sb[j], a3 = sb[j];
#pragma unroll 2
        for (int k = 0; k < F; k += 4) {
            float w0 = sW[k][j], w1 = sW[k + 1][j], w2 = sW[k + 2][j], w3 = sW[k + 3][j];
            float4 m0 = *(const float4*)&sx[lw + 0][k];
            float4 m1 = *(const float4*)&sx[lw + 1][k];
            float4 m2 = *(const float4*)&sx[lw + 2][k];
            float4 m3 = *(const float4*)&sx[lw + 3][k];
            a0 += m0.x * w0 + m0.y * w1 + m0.z * w2 + m0.w * w3;
            a1 += m1.x * w0 + m1.y * w1 + m1.z * w2 + m1.w * w3;
            a2 += m2.x * w0 + m2.y * w1 + m2.z * w2 + m2.w * w3;
            a3 += m3.x * w0 + m3.y * w1 + m3.z * w2 + m3.w * w3;
        }
        int r0 = row0 + lw;
        if (r0 + 0 < n) out[(size_t)(r0 + 0) * 64 + j] = f2b(a0);
        if (r0 + 1 < n) out[(size_t)(r0 + 1) * 64 + j] = f2b(a1);
        if (r0 + 2 < n) out[(size_t)(r0 + 2) * 64 + j] = f2b(a2);
        if (r0 + 3 < n) out[(size_t)(r0 + 3) * 64 + j] = f2b(a3);
    }
}

// agg[dst[e], :] += h[src[e], :]   (one wave per edge, lane = feature)
// cnt != nullptr: also accumulate degree (fused count, conv1 only)
__global__ void agg_kernel(const bf16* __restrict__ h, const int* __restrict__ src,
                           const int* __restrict__ dst, float* __restrict__ agg,
                           float* __restrict__ cnt, int ne) {
    int e = blockIdx.x * 4 + (threadIdx.x >> 6);
    if (e >= ne) return;
    int lane = threadIdx.x & 63;
    int s = src[e], d = dst[e];
    float v = b2f(h[(size_t)s * 64 + lane]);
    atomicAddF(&agg[(size_t)d * 64 + lane], v);
    if (cnt && lane == 0) atomicAddF(&cnt[d], 1.0f);
}

// out[i,j] = relu( (agg[i,:]/max(cnt_i,1)) . Wl[:,j] + bl[j] + xd[i,:] . Wr[:,j] )
// Wave w owns rows lw..lw+3 of each 16-row group. The two matmuls run as TWO
// SEQUENTIAL k-loops (each proj-shaped: 4 weight scalars + 4 float4 broadcast
// reads live at a time) with unroll bounded to 2 — keeps peak register pressure
// ~proj-level, which is proven not to spill. No private arrays anywhere.
// In-place outb==xd is safe (group staged to LDS, synced, then overwritten).
// HEAD=true: fused logits = relu(t2 @ Wh1 + bh1) @ Wh2 + bh2; t2 re-staged
// wave-locally into sm (per-wave LDS program order makes this safe).
template<bool HEAD>
__global__ void sage_out_kernel(const float* __restrict__ agg, const float* __restrict__ cnt,
                                const bf16* __restrict__ xd,
                                const float* __restrict__ Wl, const float* __restrict__ bl,
                                const float* __restrict__ Wr,
                                float* __restrict__ outf, bf16* __restrict__ outb,
                                const float* __restrict__ Wh1, const float* __restrict__ bh1,
                                const float* __restrict__ Wh2, const float* __restrict__ bh2,
                                float* __restrict__ logits, int n) {
    __shared__ float sWl[64][64];
    __shared__ float sWr[64][64];
    __shared__ float sW1[HEAD ? 64 : 1][64];
    __shared__ float sbl[64];
    __shared__ float sb1[HEAD ? 64 : 1];
    __shared__ float sW2[HEAD ? 128 : 2];
    __shared__ float sb2[2];
    __shared__ float sm[16][64];
    __shared__ float sx[16][64];
    __shared__ float sc[16];
    int tid = threadIdx.x;
    for (int idx = tid; idx < 1024; idx += 256) {
        ((float4*)sWl)[idx] = ((const float4*)Wl)[idx];
        ((float4*)sWr)[idx] = ((const float4*)Wr)[idx];
        if (HEAD) ((float4*)sW1)[idx] = ((const float4*)Wh1)[idx];
    }
    if (tid < 64) sbl[tid] = bl[tid];
    if (HEAD) {
        if (tid >= 64 && tid < 128) sb1[tid - 64] = bh1[tid - 64];
        if (tid >= 128 && tid < 256) sW2[tid - 128] = Wh2[tid - 128];
        if (tid < 2) sb2[tid] = bh2[tid];
    }
    int base = blockIdx.x * 64;
    int w = tid >> 6, j = tid & 63;
    int lw = w * 4;
    for (int g = 0; g < 4; ++g) {
        int row0 = base + g * 16;
        __syncthreads();   // weights (g=0) / prior-group LDS reuse (g>0)
        {
            // stage 16 rows: agg as float4 (1/thread), xd as 4xbf16 (1/thread)
            int rr = tid >> 4, c4 = tid & 15;
            int row = row0 + rr;
            float4 a = make_float4(0.f, 0.f, 0.f, 0.f);
            float4 xv = make_float4(0.f, 0.f, 0.f, 0.f);
            if (row < n) {
                a = ((const float4*)agg)[(size_t)row * 16 + c4];
                ushort4 u = ((const ushort4*)xd)[(size_t)row * 16 + c4];
                xv.x = bfbits2f(u.x); xv.y = bfbits2f(u.y);
                xv.z = bfbits2f(u.z); xv.w = bfbits2f(u.w);
            }
            *(float4*)&sm[rr][c4 * 4] = a;
            *(float4*)&sx[rr][c4 * 4] = xv;
            if (tid < 16) sc[tid] = (row0 + tid < n) ? cnt[row0 + tid] : 1.f;
        }
        __syncthreads();
        // ---- matmul 1: accl = mean-side (sm @ Wl) ----
        float l0 = 0.f, l1 = 0.f, l2 = 0.f, l3 = 0.f;
#pragma unroll 2
        for (int k = 0; k < 64; k += 4) {
            float w0 = sWl[k][j], w1 = sWl[k + 1][j], w2 = sWl[k + 2][j], w3 = sWl[k + 3][j];
            float4 m0 = *(const float4*)&sm[lw + 0][k];
            float4 m1 = *(const float4*)&sm[lw + 1][k];
            float4 m2 = *(const float4*)&sm[lw + 2][k];
            float4 m3 = *(const float4*)&sm[lw + 3][k];
            l0 += m0.x * w0 + m0.y * w1 + m0.z * w2 + m0.w * w3;
            l1 += m1.x * w0 + m1.y * w1 + m1.z * w2 + m1.w * w3;
            l2 += m2.x * w0 + m2.y * w1 + m2.z * w2 + m2.w * w3;
            l3 += m3.x * w0 + m3.y * w1 + m3.z * w2 + m3.w * w3;
        }
        // ---- matmul 2: accr = self-side (sx @ Wr) ----
        float e0 = 0.f, e1 = 0.f, e2 = 0.f, e3 = 0.f;
#pragma unroll 2
        for (int k = 0; k < 64; k += 4) {
            float w0 = sWr[k][j], w1 = sWr[k + 1][j], w2 = sWr[k + 2][j], w3 = sWr[k + 3][j];
            float4 m0 = *(const float4*)&sx[lw + 0][k];
            float4 m1 = *(const float4*)&sx[lw + 1][k];
            float4 m2 = *(const float4*)&sx[lw + 2][k];
            float4 m3 = *(const float4*)&sx[lw + 3][k];
            e0 += m0.x * w0 + m0.y * w1 + m0.z * w2 + m0.w * w3;
            e1 += m1.x * w0 + m1.y * w1 + m1.z * w2 + m1.w * w3;
            e2 += m2.x * w0 + m2.y * w1 + m2.z * w2 + m2.w * w3;
            e3 += m3.x * w0 + m3.y * w1 + m3.z * w2 + m3.w * w3;
        }
        float i0 = 1.f / fmaxf(sc[lw + 0], 1.f);
        float i1 = 1.f / fmaxf(sc[lw + 1], 1.f);
        float i2 = 1.f / fmaxf(sc[lw + 2], 1.f);
        float i3 = 1.f / fmaxf(sc[lw + 3], 1.f);
        float v0 = fmaxf(l0 * i0 + sbl[j] + e0, 0.f);
        float v1 = fmaxf(l1 * i1 + sbl[j] + e1, 0.f);
        float v2 = fmaxf(l2 * i2 + sbl[j] + e2, 0.f);
        float v3 = fmaxf(l3 * i3 + sbl[j] + e3, 0.f);
        int r0 = row0 + lw;
        if (outf) {
            if (r0 + 0 < n) outf[(size_t)(r0 + 0) * 64 + j] = v0;
            if (r0 + 1 < n) outf[(size_t)(r0 + 1) * 64 + j] = v1;
            if (r0 + 2 < n) outf[(size_t)(r0 + 2) * 64 + j] = v2;
            if (r0 + 3 < n) outf[(size_t)(r0 + 3) * 64 + j] = v3;
        }
        if (outb) {
            if (r0 + 0 < n) outb[(size_t)(r0 + 0) * 64 + j] = f2b(v0);
            if (r0 + 1 < n) outb[(size_t)(r0 + 1) * 64 + j] = f2b(v1);
            if (r0 + 2 < n) outb[(size_t)(r0 + 2) * 64 + j] = f2b(v2);
            if (r0 + 3 < n) outb[(size_t)(r0 + 3) * 64 + j] = f2b(v3);
        }
        if (HEAD) {
            // Wave-local t2 staging: wave w exclusively owns sm rows lw..lw+3;
            // per-wave LDS ops retire in program order, so these writes are
            // ordered before the reads in the loop below (same wave only).
            sm[lw + 0][j] = v0;
            sm[lw + 1][j] = v1;
            sm[lw + 2][j] = v2;
            sm[lw + 3][j] = v3;
            float h0 = sb1[j], h1 = sb1[j], h2 = sb1[j], h3 = sb1[j];
#pragma unroll 2
            for (int k = 0; k < 64; k += 4) {
                float w0 = sW1[k][j], w1 = sW1[k + 1][j], w2 = sW1[k + 2][j], w3 = sW1[k + 3][j];
                float4 m0 = *(const float4*)&sm[lw + 0][k];
                float4 m1 = *(const float4*)&sm[lw + 1][k];
                float4 m2 = *(const float4*)&sm[lw + 2][k];
                float4 m3 = *(const float4*)&sm[lw + 3][k];
                h0 += m0.x * w0 + m0.y * w1 + m0.z * w2 + m0.w * w3;
                h1 += m1.x * w0 + m1.y * w1 + m1.z * w2 + m1.w * w3;
                h2 += m2.x * w0 + m2.y * w1 + m2.z * w2 + m2.w * w3;
                h3 += m3.x * w0 + m3.y * w1 + m3.z * w2 + m3.w * w3;
            }
            h0 = fmaxf(h0, 0.f); h1 = fmaxf(h1, 0.f);
            h2 = fmaxf(h2, 0.f); h3 = fmaxf(h3, 0.f);
            float wa = sW2[j * 2 + 0], wb = sW2[j * 2 + 1];
            float p00 = h0 * wa, p01 = h0 * wb;
            float p10 = h1 * wa, p11 = h1 * wb;
            float p20 = h2 * wa, p21 = h2 * wb;
            float p30 = h3 * wa, p31 = h3 * wb;
#pragma unroll
            for (int off = 32; off; off >>= 1) {
                p00 += __shfl_down(p00, off); p01 += __shfl_down(p01, off);
                p10 += __shfl_down(p10, off); p11 += __shfl_down(p11, off);
                p20 += __shfl_down(p20, off); p21 += __shfl_down(p21, off);
                p30 += __shfl_down(p30, off); p31 += __shfl_down(p31, off);
            }
            if (j == 0) {
                if (r0 + 0 < n) { logits[(size_t)(r0 + 0) * 2 + 0] = p00 + sb2[0];
                                  logits[(size_t)(r0 + 0) * 2 + 1] = p01 + sb2[1]; }
                if (r0 + 1 < n) { logits[(size_t)(r0 + 1) * 2 + 0] = p10 + sb2[0];
                                  logits[(size_t)(r0 + 1) * 2 + 1] = p11 + sb2[1]; }
                if (r0 + 2 < n) { logits[(size_t)(r0 + 2) * 2 + 0] = p20 + sb2[0];
                                  logits[(size_t)(r0 + 2) * 2 + 1] = p21 + sb2[1]; }
                if (r0 + 3 < n) { logits[(size_t)(r0 + 3) * 2 + 0] = p30 + sb2[0];
                                  logits[(size_t)(r0 + 3) * 2 + 1] = p31 + sb2[1]; }
            }
        }
    }
}

extern "C" void kernel_launch(void* const* d_in, const int* in_sizes, int n_in,
                              void* d_out, int out_size, void* d_ws, size_t ws_size,
                              hipStream_t stream) {
    const float* x_tx   = (const float*)d_in[0];
    const float* x_w    = (const float*)d_in[1];
    const int*   src_tw = (const int*)d_in[2];
    const int*   dst_tw = (const int*)d_in[3];
    const int*   src_wt = (const int*)d_in[4];
    const int*   dst_wt = (const int*)d_in[5];
    const float* Win_tx = (const float*)d_in[6];
    const float* bin_tx = (const float*)d_in[7];
    const float* Win_w  = (const float*)d_in[8];
    const float* bin_w  = (const float*)d_in[9];
    const float* Wl1_tw = (const float*)d_in[10];
    const float* bl1_tw = (const float*)d_in[11];
    const float* Wr1_tw = (const float*)d_in[12];
    const float* Wl1_wt = (const float*)d_in[13];
    const float* bl1_wt = (const float*)d_in[14];
    const float* Wr1_wt = (const float*)d_in[15];
    const float* Wl2_tw = (const float*)d_in[16];
    const float* bl2_tw = (const float*)d_in[17];
    const float* Wr2_tw = (const float*)d_in[18];
    const float* Wl2_wt = (const float*)d_in[19];
    const float* bl2_wt = (const float*)d_in[20];
    const float* Wr2_wt = (const float*)d_in[21];
    const float* Wh1    = (const float*)d_in[22];
    const float* bh1    = (const float*)d_in[23];
    const float* Wh2    = (const float*)d_in[24];
    const float* bh2    = (const float*)d_in[25];

    const int n_tx  = in_sizes[0] / 64;
    const int n_w   = in_sizes[1] / 32;
    const int ne_tw = in_sizes[2];
    const int ne_wt = in_sizes[4];

    // workspace layout (~485 MB) — aggE and aggC are SEPARATE (both alive in conv1)
    float* aggE   = (float*)d_ws;                         // n_tx*64 f32 : agg into tx
    float* aggC   = aggE + (size_t)n_tx * 64;             // n_w *64 f32 : agg into wallets
    bf16*  A      = (bf16*)(aggC + (size_t)n_w * 64);     // n_tx*64 bf16: h_tx -> t1 (in-place)
    bf16*  B      = A + (size_t)n_tx * 64;                // n_w *64 bf16: h_w  -> w1 (in-place)
    float* cnt_w  = (float*)(B + (size_t)n_w * 64);       // n_w
    float* cnt_tx = cnt_w + n_w;                          // n_tx

    float* out_logits = (float*)d_out;
    float* out_t2 = out_logits + (size_t)n_tx * 2;
    float* out_w2 = out_t2 + (size_t)n_tx * 64;

    const size_t bytes_aggw  = (size_t)n_w * 64 * sizeof(float);
    const size_t bytes_aggtx = (size_t)n_tx * 64 * sizeof(float);

    dim3 blk(256);
    int grid_proj_tx = (n_tx + 63) / 64;
    int grid_proj_w  = (n_w + 63) / 64;
    int grid_agg_tw  = (ne_tw + 3) / 4;
    int grid_agg_wt  = (ne_wt + 3) / 4;

    // zero counters + agg buffers, project inputs
    hipMemsetAsync(cnt_w, 0, (size_t)n_w * sizeof(float), stream);
    hipMemsetAsync(cnt_tx, 0, (size_t)n_tx * sizeof(float), stream);
    hipMemsetAsync(aggE, 0, bytes_aggtx, stream);
    hipMemsetAsync(aggC, 0, bytes_aggw, stream);
    proj_kernel<64><<<grid_proj_tx, blk, 0, stream>>>(x_tx, Win_tx, bin_tx, A, n_tx);
    proj_kernel<32><<<grid_proj_w, blk, 0, stream>>>(x_w, Win_w, bin_w, B, n_w);

    // conv1: BOTH aggregations first (fused degree count), THEN both epilogues
    agg_kernel<<<grid_agg_tw, blk, 0, stream>>>(A, src_tw, dst_tw, aggC, cnt_w, ne_tw);  // h_tx -> w
    agg_kernel<<<grid_agg_wt, blk, 0, stream>>>(B, src_wt, dst_wt, aggE, cnt_tx, ne_wt); // h_w  -> tx
    sage_out_kernel<false><<<grid_proj_w, blk, 0, stream>>>(
        aggC, cnt_w, B, Wl1_tw, bl1_tw, Wr1_tw,
        nullptr, B, nullptr, nullptr, nullptr, nullptr, nullptr, n_w);            // w1 (in-place B)
    sage_out_kernel<false><<<grid_proj_tx, blk, 0, stream>>>(
        aggE, cnt_tx, A, Wl1_wt, bl1_wt, Wr1_wt,
        nullptr, A, nullptr, nullptr, nullptr, nullptr, nullptr, n_tx);           // t1 (in-place A)

    // conv2: re-zero agg buffers, both aggregations (from t1=A, w1=B), both epilogues
    hipMemsetAsync(aggC, 0, bytes_aggw, stream);
    hipMemsetAsync(aggE, 0, bytes_aggtx, stream);
    agg_kernel<<<grid_agg_tw, blk, 0, stream>>>(A, src_tw, dst_tw, aggC, nullptr, ne_tw); // t1 -> w
    agg_kernel<<<grid_agg_wt, blk, 0, stream>>>(B, src_wt, dst_wt, aggE, nullptr, ne_wt); // w1 -> tx
    sage_out_kernel<false><<<grid_proj_w, blk, 0, stream>>>(
        aggC, cnt_w, B, Wl2_tw, bl2_tw, Wr2_tw,
        out_w2, nullptr, nullptr, nullptr, nullptr, nullptr, nullptr, n_w);       // w2 -> f32 out
    // t2 epilogue + fused head: writes out_t2 AND out_logits in one pass
    sage_out_kernel<true><<<grid_proj_tx, blk, 0, stream>>>(
        aggE, cnt_tx, A, Wl2_wt, bl2_wt, Wr2_wt,
        out_t2, nullptr, Wh1, bh1, Wh2, bh2, out_logits, n_tx);                   // t2 + logits
}

// Round 4
// 3258.805 us; speedup vs baseline: 13.7992x; 1.4081x over previous
//
#include <hip/hip_runtime.h>
#include <hip/hip_bf16.h>

typedef __hip_bfloat16 bf16;
typedef __attribute__((ext_vector_type(8))) short bf16x8;   // 8 bf16 = 4 VGPR
typedef __attribute__((ext_vector_type(4))) float f32x4;    // MFMA accumulator

__device__ __forceinline__ float b2f(bf16 v) { return __bfloat162float(v); }
__device__ __forceinline__ bf16 f2b(float v) { return __float2bfloat16(v); }
__device__ __forceinline__ float bfbits2f(unsigned short u) {
    return __uint_as_float((unsigned int)u << 16);
}
__device__ __forceinline__ unsigned short f2bb(float v) {   // RNE f32->bf16 bits
    unsigned int u = __float_as_uint(v);
    u += 0x7fffu + ((u >> 16) & 1u);
    return (unsigned short)(u >> 16);
}

__device__ __forceinline__ void atomicAddF(float* p, float v) {
    unsafeAtomicAdd(p, v);   // hardware global_atomic_add_f32 on gfx950
}

__device__ __forceinline__ f32x4 mfma16(bf16x8 a, bf16x8 b, f32x4 c) {
    return __builtin_amdgcn_mfma_f32_16x16x32_bf16(a, b, c, 0, 0, 0);
}

// Gather a B-fragment: rows k0..k0+7 of column col from row-major W[64][64] f32.
// All loads L2-hot (weights tiny, every block reads the same 16 KB).
__device__ __forceinline__ bf16x8 load_bfrag(const float* __restrict__ W, int k0, int col) {
    bf16x8 f;
#pragma unroll
    for (int j = 0; j < 8; ++j)
        f[j] = (short)f2bb(W[(size_t)(k0 + j) * 64 + col]);
    return f;
}

// Swizzled byte offsets (G4: XOR row-bits into the 16B-slot index so the
// 128B/256B-stride fragment reads don't all land in one bank group).
__device__ __forceinline__ int swzA(int row, int b) {   // [64][128 bf16] tile, 256B rows
    return row * 256 + (b ^ ((row & 7) << 4));
}
__device__ __forceinline__ int swzH(int row, int b) {   // [64][64 bf16] tile, 128B rows
    return row * 128 + (b ^ ((row & 7) << 4));
}

// out[i,j] = relu( (agg[i,:]/max(cnt_i,1)) . Wl[:,j] + bl[j] + xd[i,:] . Wr[:,j] )
// MFMA version: the two matmuls fuse into one K=128 GEMM with A = [mean | xd]
// (bf16, staged swizzled in LDS) and B = [Wl ; Wr] (bf16 fragments in registers,
// loaded once per block). Wave w computes rows w*16..w*16+15 of each 64-row
// group; block covers 512 rows (8 groups). C/D layout: col=lane&15,
// row=(lane>>4)*4+reg. In-place outb==xd is safe (group staged, synced, then
// overwritten). HEAD: t2 restaged bf16 wave-locally into sH (per-wave LDS
// program order), one more K=64 MFMA GEMM, then 16-lane shfl_xor reduce for
// the 64->2 contraction.
template<bool HEAD>
__global__ __launch_bounds__(256, 2)
void sage_mfma_kernel(const float* __restrict__ agg, const float* __restrict__ cnt,
                      const bf16* __restrict__ xd,
                      const float* __restrict__ Wl, const float* __restrict__ bl,
                      const float* __restrict__ Wr,
                      float* __restrict__ outf, bf16* __restrict__ outb,
                      const float* __restrict__ Wh1, const float* __restrict__ bh1,
                      const float* __restrict__ Wh2, const float* __restrict__ bh2,
                      float* __restrict__ logits, int n) {
    __shared__ __align__(16) short sA[64 * 128];              // 16 KB
    __shared__ __align__(16) short sH[HEAD ? 64 * 64 : 8];    // 8 KB (HEAD)
    int tid = threadIdx.x;
    int lane = tid & 63, w = tid >> 6;
    int lm = lane & 15, lq = lane >> 4;

    // --- weight fragments: once per block, held in registers ---
    bf16x8 wc[4][4];   // [col-tile][k-step]; ks 0,1 = Wl(k0=0,32), ks 2,3 = Wr
    bf16x8 wh[4][2];
    float blv[4], h1v[4], w2a[4], w2b[4];
#pragma unroll
    for (int ct = 0; ct < 4; ++ct) {
        int col = ct * 16 + lm;
        wc[ct][0] = load_bfrag(Wl, lq * 8, col);
        wc[ct][1] = load_bfrag(Wl, 32 + lq * 8, col);
        wc[ct][2] = load_bfrag(Wr, lq * 8, col);
        wc[ct][3] = load_bfrag(Wr, 32 + lq * 8, col);
        blv[ct] = bl[col];
        if (HEAD) {
            wh[ct][0] = load_bfrag(Wh1, lq * 8, col);
            wh[ct][1] = load_bfrag(Wh1, 32 + lq * 8, col);
            h1v[ct] = bh1[col];
            w2a[ct] = Wh2[col * 2 + 0];
            w2b[ct] = Wh2[col * 2 + 1];
        }
    }
    float b20 = 0.f, b21 = 0.f;
    if (HEAD) { b20 = bh2[0]; b21 = bh2[1]; }

    const float4*  agg4 = (const float4*)agg;
    const ushort4* xd4  = (const ushort4*)xd;

    for (int g = 0; g < 8; ++g) {
        int row0 = blockIdx.x * 512 + g * 64;
        if (row0 >= n) break;
        __syncthreads();   // protect sA reuse (prev group's fragment reads done)
        // --- stage mean into cols 0..63 (1024 granules, 4/thread) ---
#pragma unroll
        for (int i = 0; i < 4; ++i) {
            int idx = tid + i * 256;
            int row = idx >> 4, c4 = idx & 15;
            int grow = row0 + row;
            float4 a = make_float4(0.f, 0.f, 0.f, 0.f);
            float inv = 1.f;
            if (grow < n) {
                a = agg4[(size_t)grow * 16 + c4];
                inv = 1.f / fmaxf(cnt[grow], 1.f);
            }
            ushort4 p;
            p.x = f2bb(a.x * inv); p.y = f2bb(a.y * inv);
            p.z = f2bb(a.z * inv); p.w = f2bb(a.w * inv);
            *(ushort4*)((char*)sA + swzA(row, c4 * 8)) = p;
        }
        // --- stage xd into cols 64..127 ---
#pragma unroll
        for (int i = 0; i < 4; ++i) {
            int idx = tid + i * 256;
            int row = idx >> 4, c4 = idx & 15;
            int grow = row0 + row;
            ushort4 u = make_ushort4(0, 0, 0, 0);
            if (grow < n) u = xd4[(size_t)grow * 16 + c4];
            *(ushort4*)((char*)sA + swzA(row, 128 + c4 * 8)) = u;
        }
        __syncthreads();

        // --- compute: wave w owns rows w*16..w*16+15 ---
        int arow = w * 16 + lm;   // A-fragment row for this lane
        bf16x8 a0 = *(const bf16x8*)((char*)sA + swzA(arow, lq * 16));
        bf16x8 a1 = *(const bf16x8*)((char*)sA + swzA(arow, 64 + lq * 16));
        bf16x8 a2 = *(const bf16x8*)((char*)sA + swzA(arow, 128 + lq * 16));
        bf16x8 a3 = *(const bf16x8*)((char*)sA + swzA(arow, 192 + lq * 16));
#pragma unroll
        for (int ct = 0; ct < 4; ++ct) {
            f32x4 acc = {0.f, 0.f, 0.f, 0.f};
            acc = mfma16(a0, wc[ct][0], acc);
            acc = mfma16(a1, wc[ct][1], acc);
            acc = mfma16(a2, wc[ct][2], acc);
            acc = mfma16(a3, wc[ct][3], acc);
            int col = ct * 16 + lm;
#pragma unroll
            for (int r = 0; r < 4; ++r) {
                int lrow = w * 16 + lq * 4 + r;   // local row of this output elem
                int grow = row0 + lrow;
                float v = fmaxf(acc[r] + blv[ct], 0.f);
                if (grow < n) {
                    if (outf) outf[(size_t)grow * 64 + col] = v;
                    if (outb) outb[(size_t)grow * 64 + col] = f2b(v);
                }
                if (HEAD)   // wave-local restage; same wave reads below
                    *(short*)((char*)sH + swzH(lrow, col * 2)) = (short)f2bb(v);
            }
        }
        if (HEAD) {
            bf16x8 h0 = *(const bf16x8*)((char*)sH + swzH(arow, lq * 16));
            bf16x8 h1 = *(const bf16x8*)((char*)sH + swzH(arow, 64 + lq * 16));
            float qa0 = 0.f, qa1 = 0.f, qa2 = 0.f, qa3 = 0.f;
            float qb0 = 0.f, qb1 = 0.f, qb2 = 0.f, qb3 = 0.f;
#pragma unroll
            for (int ct = 0; ct < 4; ++ct) {
                f32x4 acc = {0.f, 0.f, 0.f, 0.f};
                acc = mfma16(h0, wh[ct][0], acc);
                acc = mfma16(h1, wh[ct][1], acc);
                float hb = h1v[ct];
                float h_0 = fmaxf(acc[0] + hb, 0.f);
                float h_1 = fmaxf(acc[1] + hb, 0.f);
                float h_2 = fmaxf(acc[2] + hb, 0.f);
                float h_3 = fmaxf(acc[3] + hb, 0.f);
                qa0 += h_0 * w2a[ct]; qb0 += h_0 * w2b[ct];
                qa1 += h_1 * w2a[ct]; qb1 += h_1 * w2b[ct];
                qa2 += h_2 * w2a[ct]; qb2 += h_2 * w2b[ct];
                qa3 += h_3 * w2a[ct]; qb3 += h_3 * w2b[ct];
            }
#pragma unroll
            for (int m = 8; m; m >>= 1) {   // reduce over the 16-lane quad
                qa0 += __shfl_xor(qa0, m); qb0 += __shfl_xor(qb0, m);
                qa1 += __shfl_xor(qa1, m); qb1 += __shfl_xor(qb1, m);
                qa2 += __shfl_xor(qa2, m); qb2 += __shfl_xor(qb2, m);
                qa3 += __shfl_xor(qa3, m); qb3 += __shfl_xor(qb3, m);
            }
            int rowb = row0 + w * 16 + lq * 4;
            if (lm == 0) {
                if (rowb + 0 < n) { logits[(size_t)(rowb + 0) * 2 + 0] = qa0 + b20;
                                    logits[(size_t)(rowb + 0) * 2 + 1] = qb0 + b21; }
                if (rowb + 1 < n) { logits[(size_t)(rowb + 1) * 2 + 0] = qa1 + b20;
                                    logits[(size_t)(rowb + 1) * 2 + 1] = qb1 + b21; }
                if (rowb + 2 < n) { logits[(size_t)(rowb + 2) * 2 + 0] = qa2 + b20;
                                    logits[(size_t)(rowb + 2) * 2 + 1] = qb2 + b21; }
                if (rowb + 3 < n) { logits[(size_t)(rowb + 3) * 2 + 0] = qa3 + b20;
                                    logits[(size_t)(rowb + 3) * 2 + 1] = qb3 + b21; }
            }
        }
    }
}

// out[i,j] = sum_k x[i,k]*W[k,j] + b[j]   (x,W,b f32 -> out bf16), no relu
// (round-3 proven VALU version; named scalars, unroll bounded)
template<int F>
__global__ void proj_kernel(const float* __restrict__ x, const float* __restrict__ W,
                            const float* __restrict__ b, bf16* __restrict__ out, int n) {
    __shared__ float sW[F][64];
    __shared__ float sb[64];
    __shared__ float sx[16][F];
    int tid = threadIdx.x;
    for (int idx = tid; idx < F * 16; idx += 256)
        ((float4*)sW)[idx] = ((const float4*)W)[idx];
    if (tid < 64) sb[tid] = b[tid];
    int base = blockIdx.x * 64;
    int w = tid >> 6, j = tid & 63;
    int lw = w * 4;
    for (int g = 0; g < 4; ++g) {
        int row0 = base + g * 16;
        __syncthreads();
        for (int idx = tid; idx < 4 * F; idx += 256) {
            int rr = idx / (F / 4), c4 = idx - rr * (F / 4);
            int row = row0 + rr;
            float4 v = (row < n) ? ((const float4*)x)[(size_t)row * (F / 4) + c4]
                                 : make_float4(0.f, 0.f, 0.f, 0.f);
            *(float4*)&sx[rr][c4 * 4] = v;
        }
        __syncthreads();
        float a0 = sb[j], a1 = sb[j], a2 = sb[j], a3 = sb[j];
#pragma unroll 2
        for (int k = 0; k < F; k += 4) {
            float w0 = sW[k][j], w1 = sW[k + 1][j], w2 = sW[k + 2][j], w3 = sW[k + 3][j];
            float4 m0 = *(const float4*)&sx[lw + 0][k];
            float4 m1 = *(const float4*)&sx[lw + 1][k];
            float4 m2 = *(const float4*)&sx[lw + 2][k];
            float4 m3 = *(const float4*)&sx[lw + 3][k];
            a0 += m0.x * w0 + m0.y * w1 + m0.z * w2 + m0.w * w3;
            a1 += m1.x * w0 + m1.y * w1 + m1.z * w2 + m1.w * w3;
            a2 += m2.x * w0 + m2.y * w1 + m2.z * w2 + m2.w * w3;
            a3 += m3.x * w0 + m3.y * w1 + m3.z * w2 + m3.w * w3;
        }
        int r0 = row0 + lw;
        if (r0 + 0 < n) out[(size_t)(r0 + 0) * 64 + j] = f2b(a0);
        if (r0 + 1 < n) out[(size_t)(r0 + 1) * 64 + j] = f2b(a1);
        if (r0 + 2 < n) out[(size_t)(r0 + 2) * 64 + j] = f2b(a2);
        if (r0 + 3 < n) out[(size_t)(r0 + 3) * 64 + j] = f2b(a3);
    }
}

// agg[dst[e], :] += h[src[e], :]   (one wave per edge, lane = feature)
// cnt != nullptr: also accumulate degree (fused count, conv1 only)
__global__ void agg_kernel(const bf16* __restrict__ h, const int* __restrict__ src,
                           const int* __restrict__ dst, float* __restrict__ agg,
                           float* __restrict__ cnt, int ne) {
    int e = blockIdx.x * 4 + (threadIdx.x >> 6);
    if (e >= ne) return;
    int lane = threadIdx.x & 63;
    int s = src[e], d = dst[e];
    float v = b2f(h[(size_t)s * 64 + lane]);
    atomicAddF(&agg[(size_t)d * 64 + lane], v);
    if (cnt && lane == 0) atomicAddF(&cnt[d], 1.0f);
}

extern "C" void kernel_launch(void* const* d_in, const int* in_sizes, int n_in,
                              void* d_out, int out_size, void* d_ws, size_t ws_size,
                              hipStream_t stream) {
    const float* x_tx   = (const float*)d_in[0];
    const float* x_w    = (const float*)d_in[1];
    const int*   src_tw = (const int*)d_in[2];
    const int*   dst_tw = (const int*)d_in[3];
    const int*   src_wt = (const int*)d_in[4];
    const int*   dst_wt = (const int*)d_in[5];
    const float* Win_tx = (const float*)d_in[6];
    const float* bin_tx = (const float*)d_in[7];
    const float* Win_w  = (const float*)d_in[8];
    const float* bin_w  = (const float*)d_in[9];
    const float* Wl1_tw = (const float*)d_in[10];
    const float* bl1_tw = (const float*)d_in[11];
    const float* Wr1_tw = (const float*)d_in[12];
    const float* Wl1_wt = (const float*)d_in[13];
    const float* bl1_wt = (const float*)d_in[14];
    const float* Wr1_wt = (const float*)d_in[15];
    const float* Wl2_tw = (const float*)d_in[16];
    const float* bl2_tw = (const float*)d_in[17];
    const float* Wr2_tw = (const float*)d_in[18];
    const float* Wl2_wt = (const float*)d_in[19];
    const float* bl2_wt = (const float*)d_in[20];
    const float* Wr2_wt = (const float*)d_in[21];
    const float* Wh1    = (const float*)d_in[22];
    const float* bh1    = (const float*)d_in[23];
    const float* Wh2    = (const float*)d_in[24];
    const float* bh2    = (const float*)d_in[25];

    const int n_tx  = in_sizes[0] / 64;
    const int n_w   = in_sizes[1] / 32;
    const int ne_tw = in_sizes[2];
    const int ne_wt = in_sizes[4];

    // workspace layout (~485 MB) — aggE and aggC are SEPARATE (both alive in conv1)
    float* aggE   = (float*)d_ws;                         // n_tx*64 f32 : agg into tx
    float* aggC   = aggE + (size_t)n_tx * 64;             // n_w *64 f32 : agg into wallets
    bf16*  A      = (bf16*)(aggC + (size_t)n_w * 64);     // n_tx*64 bf16: h_tx -> t1 (in-place)
    bf16*  B      = A + (size_t)n_tx * 64;                // n_w *64 bf16: h_w  -> w1 (in-place)
    float* cnt_w  = (float*)(B + (size_t)n_w * 64);       // n_w
    float* cnt_tx = cnt_w + n_w;                          // n_tx

    float* out_logits = (float*)d_out;
    float* out_t2 = out_logits + (size_t)n_tx * 2;
    float* out_w2 = out_t2 + (size_t)n_tx * 64;

    const size_t bytes_aggw  = (size_t)n_w * 64 * sizeof(float);
    const size_t bytes_aggtx = (size_t)n_tx * 64 * sizeof(float);

    dim3 blk(256);
    int grid_proj_tx = (n_tx + 63) / 64;
    int grid_proj_w  = (n_w + 63) / 64;
    int grid_sage_tx = (n_tx + 511) / 512;
    int grid_sage_w  = (n_w + 511) / 512;
    int grid_agg_tw  = (ne_tw + 3) / 4;
    int grid_agg_wt  = (ne_wt + 3) / 4;

    // zero counters + agg buffers, project inputs
    hipMemsetAsync(cnt_w, 0, (size_t)n_w * sizeof(float), stream);
    hipMemsetAsync(cnt_tx, 0, (size_t)n_tx * sizeof(float), stream);
    hipMemsetAsync(aggE, 0, bytes_aggtx, stream);
    hipMemsetAsync(aggC, 0, bytes_aggw, stream);
    proj_kernel<64><<<grid_proj_tx, blk, 0, stream>>>(x_tx, Win_tx, bin_tx, A, n_tx);
    proj_kernel<32><<<grid_proj_w, blk, 0, stream>>>(x_w, Win_w, bin_w, B, n_w);

    // conv1: BOTH aggregations first (fused degree count), THEN both epilogues
    agg_kernel<<<grid_agg_tw, blk, 0, stream>>>(A, src_tw, dst_tw, aggC, cnt_w, ne_tw);  // h_tx -> w
    agg_kernel<<<grid_agg_wt, blk, 0, stream>>>(B, src_wt, dst_wt, aggE, cnt_tx, ne_wt); // h_w  -> tx
    sage_mfma_kernel<false><<<grid_sage_w, blk, 0, stream>>>(
        aggC, cnt_w, B, Wl1_tw, bl1_tw, Wr1_tw,
        nullptr, B, nullptr, nullptr, nullptr, nullptr, nullptr, n_w);            // w1 (in-place B)
    sage_mfma_kernel<false><<<grid_sage_tx, blk, 0, stream>>>(
        aggE, cnt_tx, A, Wl1_wt, bl1_wt, Wr1_wt,
        nullptr, A, nullptr, nullptr, nullptr, nullptr, nullptr, n_tx);           // t1 (in-place A)

    // conv2: re-zero agg buffers, both aggregations (from t1=A, w1=B), both epilogues
    hipMemsetAsync(aggC, 0, bytes_aggw, stream);
    hipMemsetAsync(aggE, 0, bytes_aggtx, stream);
    agg_kernel<<<grid_agg_tw, blk, 0, stream>>>(A, src_tw, dst_tw, aggC, nullptr, ne_tw); // t1 -> w
    agg_kernel<<<grid_agg_wt, blk, 0, stream>>>(B, src_wt, dst_wt, aggE, nullptr, ne_wt); // w1 -> tx
    sage_mfma_kernel<false><<<grid_sage_w, blk, 0, stream>>>(
        aggC, cnt_w, B, Wl2_tw, bl2_tw, Wr2_tw,
        out_w2, nullptr, nullptr, nullptr, nullptr, nullptr, nullptr, n_w);       // w2 -> f32 out
    // t2 epilogue + fused head: writes out_t2 AND out_logits in one pass
    sage_mfma_kernel<true><<<grid_sage_tx, blk, 0, stream>>>(
        aggE, cnt_tx, A, Wl2_wt, bl2_wt, Wr2_wt,
        out_t2, nullptr, Wh1, bh1, Wh2, bh2, out_logits, n_tx);                   // t2 + logits
}

// Round 5
// 2246.334 us; speedup vs baseline: 20.0188x; 1.4507x over previous
//
#include <hip/hip_runtime.h>
#include <hip/hip_bf16.h>

typedef __hip_bfloat16 bf16;
typedef __attribute__((ext_vector_type(8))) short bf16x8;   // 8 bf16 = 4 VGPR
typedef __attribute__((ext_vector_type(4))) float f32x4;    // MFMA accumulator

__device__ __forceinline__ float b2f(bf16 v) { return __bfloat162float(v); }
__device__ __forceinline__ bf16 f2b(float v) { return __float2bfloat16(v); }
__device__ __forceinline__ unsigned short f2bb(float v) {   // RNE f32->bf16 bits
    unsigned int u = __float_as_uint(v);
    u += 0x7fffu + ((u >> 16) & 1u);
    return (unsigned short)(u >> 16);
}

__device__ __forceinline__ f32x4 mfma16(bf16x8 a, bf16x8 b, f32x4 c) {
    return __builtin_amdgcn_mfma_f32_16x16x32_bf16(a, b, c, 0, 0, 0);
}

// Gather a B-fragment: rows k0..k0+7 of column col from row-major W[64][64] f32.
__device__ __forceinline__ bf16x8 load_bfrag(const float* __restrict__ W, int k0, int col) {
    bf16x8 f;
#pragma unroll
    for (int j = 0; j < 8; ++j)
        f[j] = (short)f2bb(W[(size_t)(k0 + j) * 64 + col]);
    return f;
}

// Swizzled byte offsets (G4: XOR row-bits into the 16B-slot index).
__device__ __forceinline__ int swzA(int row, int b) {   // [64][128 bf16] tile, 256B rows
    return row * 256 + (b ^ ((row & 7) << 4));
}
__device__ __forceinline__ int swzH(int row, int b) {   // [64][64 bf16] tile, 128B rows
    return row * 128 + (b ^ ((row & 7) << 4));
}

// ======================= CSR build =======================
__global__ void count_int_kernel(const int* __restrict__ dst, int* __restrict__ deg, int ne) {
    int e = blockIdx.x * 256 + threadIdx.x;
    if (e < ne) atomicAdd(&deg[dst[e]], 1);
}

// block-local exclusive scan over 1024 elems (256 thr x 4); writes block totals
__global__ void scan1_kernel(const int* __restrict__ deg, int* __restrict__ excl,
                             int* __restrict__ partial, int n) {
    __shared__ int sT[256];
    int tid = threadIdx.x;
    int base = blockIdx.x * 1024 + tid * 4;
    int v0 = (base + 0 < n) ? deg[base + 0] : 0;
    int v1 = (base + 1 < n) ? deg[base + 1] : 0;
    int v2 = (base + 2 < n) ? deg[base + 2] : 0;
    int v3 = (base + 3 < n) ? deg[base + 3] : 0;
    int t = v0 + v1 + v2 + v3;
    sT[tid] = t;
    __syncthreads();
    for (int off = 1; off < 256; off <<= 1) {   // Hillis-Steele inclusive
        int x = (tid >= off) ? sT[tid - off] : 0;
        __syncthreads();
        sT[tid] += x;
        __syncthreads();
    }
    int et = sT[tid] - t;
    if (tid == 255) partial[blockIdx.x] = sT[255];
    if (base + 0 < n) excl[base + 0] = et;
    if (base + 1 < n) excl[base + 1] = et + v0;
    if (base + 2 < n) excl[base + 2] = et + v0 + v1;
    if (base + 3 < n) excl[base + 3] = et + v0 + v1 + v2;
}

// single-block exclusive scan of the partials (np <= a few thousand)
__global__ void scan2_kernel(int* __restrict__ partial, int np) {
    __shared__ int sT[256];
    __shared__ int carry;
    int tid = threadIdx.x;
    if (tid == 0) carry = 0;
    __syncthreads();
    for (int c = 0; c < np; c += 256) {
        int i = c + tid;
        int v = (i < np) ? partial[i] : 0;
        sT[tid] = v;
        __syncthreads();
        for (int off = 1; off < 256; off <<= 1) {
            int x = (tid >= off) ? sT[tid - off] : 0;
            __syncthreads();
            sT[tid] += x;
            __syncthreads();
        }
        int incl = sT[tid];
        int total = sT[255];
        if (i < np) partial[i] = carry + incl - v;
        __syncthreads();
        if (tid == 0) carry += total;
        __syncthreads();
    }
}

// rowptr[i] = cursor[i] = excl[i] + partial[i>>10]  (cursor may alias excl)
__global__ void scan3_kernel(const int* __restrict__ excl, const int* __restrict__ partial,
                             int* __restrict__ rowptr, int* __restrict__ cursor, int n) {
    int i = blockIdx.x * 256 + threadIdx.x;
    if (i < n) {
        int v = excl[i] + partial[i >> 10];
        rowptr[i] = v;
        cursor[i] = v;
    }
}

__global__ void scatter_kernel(const int* __restrict__ src, const int* __restrict__ dst,
                               int* __restrict__ cursor, int* __restrict__ col, int ne) {
    int e = blockIdx.x * 256 + threadIdx.x;
    if (e < ne) {
        int p = atomicAdd(&cursor[dst[e]], 1);
        col[p] = src[e];
    }
}

// ======================= gather mean =======================
// mean[i,:] = (1/max(deg_i,1)) * sum_{e in row i} h[col[e], :]   (bf16 out)
// One wave per dst row, lane = feature. No atomics.
__global__ __launch_bounds__(256)
void gather_mean_kernel(const bf16* __restrict__ h, const int* __restrict__ rowptr,
                        const int* __restrict__ deg, const int* __restrict__ col,
                        bf16* __restrict__ mean, int n) {
    int row = blockIdx.x * 4 + (threadIdx.x >> 6);
    if (row >= n) return;
    int lane = threadIdx.x & 63;
    int base = rowptr[row];
    int d = deg[row];
    float acc = 0.f;
    int e = 0;
    for (; e + 4 <= d; e += 4) {
        int s0 = col[base + e + 0], s1 = col[base + e + 1];
        int s2 = col[base + e + 2], s3 = col[base + e + 3];
        acc += b2f(h[(size_t)s0 * 64 + lane]) + b2f(h[(size_t)s1 * 64 + lane])
             + b2f(h[(size_t)s2 * 64 + lane]) + b2f(h[(size_t)s3 * 64 + lane]);
    }
    for (; e < d; ++e)
        acc += b2f(h[(size_t)col[base + e] * 64 + lane]);
    float m = acc / fmaxf((float)d, 1.f);
    mean[(size_t)row * 64 + lane] = f2b(m);
}

// ======================= SAGE epilogue (MFMA) =======================
// out[i,j] = relu( mean[i,:] . Wl[:,j] + bl[j] + xd[i,:] . Wr[:,j] )
// One K=128 GEMM: A = [mean | xd] (bf16, swizzled LDS), B = [Wl ; Wr] (bf16
// register fragments, loaded once per block). Wave w owns rows w*16..w*16+15
// of each 64-row group; block covers 512 rows. C/D: col=lane&15,
// row=(lane>>4)*4+reg. In-place outb==xd safe (staged, synced, overwritten).
// HEAD: t2 restaged bf16 wave-locally into sH, K=64 MFMA GEMM, 16-lane
// shfl_xor reduce for the 64->2 contraction.
template<bool HEAD>
__global__ __launch_bounds__(256, 2)
void sage_mfma_kernel(const bf16* __restrict__ mean, const bf16* __restrict__ xd,
                      const float* __restrict__ Wl, const float* __restrict__ bl,
                      const float* __restrict__ Wr,
                      float* __restrict__ outf, bf16* __restrict__ outb,
                      const float* __restrict__ Wh1, const float* __restrict__ bh1,
                      const float* __restrict__ Wh2, const float* __restrict__ bh2,
                      float* __restrict__ logits, int n) {
    __shared__ __align__(16) short sA[64 * 128];              // 16 KB
    __shared__ __align__(16) short sH[HEAD ? 64 * 64 : 8];    // 8 KB (HEAD)
    int tid = threadIdx.x;
    int lane = tid & 63, w = tid >> 6;
    int lm = lane & 15, lq = lane >> 4;

    // --- weight fragments: once per block, held in registers ---
    bf16x8 wc[4][4];   // [col-tile][k-step]; ks 0,1 = Wl(k0=0,32), ks 2,3 = Wr
    bf16x8 wh[4][2];
    float blv[4], h1v[4], w2a[4], w2b[4];
#pragma unroll
    for (int ct = 0; ct < 4; ++ct) {
        int col = ct * 16 + lm;
        wc[ct][0] = load_bfrag(Wl, lq * 8, col);
        wc[ct][1] = load_bfrag(Wl, 32 + lq * 8, col);
        wc[ct][2] = load_bfrag(Wr, lq * 8, col);
        wc[ct][3] = load_bfrag(Wr, 32 + lq * 8, col);
        blv[ct] = bl[col];
        if (HEAD) {
            wh[ct][0] = load_bfrag(Wh1, lq * 8, col);
            wh[ct][1] = load_bfrag(Wh1, 32 + lq * 8, col);
            h1v[ct] = bh1[col];
            w2a[ct] = Wh2[col * 2 + 0];
            w2b[ct] = Wh2[col * 2 + 1];
        }
    }
    float b20 = 0.f, b21 = 0.f;
    if (HEAD) { b20 = bh2[0]; b21 = bh2[1]; }

    const bf16x8* mean8 = (const bf16x8*)mean;
    const bf16x8* xd8   = (const bf16x8*)xd;

    for (int g = 0; g < 8; ++g) {
        int row0 = blockIdx.x * 512 + g * 64;
        if (row0 >= n) break;
        __syncthreads();   // protect sA reuse (prev group's fragment reads done)
        // stage mean -> cols 0..63, xd -> cols 64..127 (16B granules, 2/thread each)
#pragma unroll
        for (int i = 0; i < 2; ++i) {
            int idx = tid + i * 256;             // 0..511
            int row = idx >> 3, c8 = idx & 7;    // 8x16B per 64-col row
            int grow = row0 + row;
            bf16x8 m, u;
#pragma unroll
            for (int j = 0; j < 8; ++j) { m[j] = 0; u[j] = 0; }
            if (grow < n) {
                m = mean8[(size_t)grow * 8 + c8];
                u = xd8[(size_t)grow * 8 + c8];
            }
            *(bf16x8*)((char*)sA + swzA(row, c8 * 16)) = m;
            *(bf16x8*)((char*)sA + swzA(row, 128 + c8 * 16)) = u;
        }
        __syncthreads();

        // --- compute: wave w owns rows w*16..w*16+15 ---
        int arow = w * 16 + lm;
        bf16x8 a0 = *(const bf16x8*)((char*)sA + swzA(arow, lq * 16));
        bf16x8 a1 = *(const bf16x8*)((char*)sA + swzA(arow, 64 + lq * 16));
        bf16x8 a2 = *(const bf16x8*)((char*)sA + swzA(arow, 128 + lq * 16));
        bf16x8 a3 = *(const bf16x8*)((char*)sA + swzA(arow, 192 + lq * 16));
#pragma unroll
        for (int ct = 0; ct < 4; ++ct) {
            f32x4 acc = {0.f, 0.f, 0.f, 0.f};
            acc = mfma16(a0, wc[ct][0], acc);
            acc = mfma16(a1, wc[ct][1], acc);
            acc = mfma16(a2, wc[ct][2], acc);
            acc = mfma16(a3, wc[ct][3], acc);
            int col = ct * 16 + lm;
#pragma unroll
            for (int r = 0; r < 4; ++r) {
                int lrow = w * 16 + lq * 4 + r;
                int grow = row0 + lrow;
                float v = fmaxf(acc[r] + blv[ct], 0.f);
                if (grow < n) {
                    if (outf) outf[(size_t)grow * 64 + col] = v;
                    if (outb) outb[(size_t)grow * 64 + col] = f2b(v);
                }
                if (HEAD)   // wave-local restage; same wave reads below
                    *(short*)((char*)sH + swzH(lrow, col * 2)) = (short)f2bb(v);
            }
        }
        if (HEAD) {
            bf16x8 h0 = *(const bf16x8*)((char*)sH + swzH(arow, lq * 16));
            bf16x8 h1 = *(const bf16x8*)((char*)sH + swzH(arow, 64 + lq * 16));
            float qa0 = 0.f, qa1 = 0.f, qa2 = 0.f, qa3 = 0.f;
            float qb0 = 0.f, qb1 = 0.f, qb2 = 0.f, qb3 = 0.f;
#pragma unroll
            for (int ct = 0; ct < 4; ++ct) {
                f32x4 acc = {0.f, 0.f, 0.f, 0.f};
                acc = mfma16(h0, wh[ct][0], acc);
                acc = mfma16(h1, wh[ct][1], acc);
                float hb = h1v[ct];
                float h_0 = fmaxf(acc[0] + hb, 0.f);
                float h_1 = fmaxf(acc[1] + hb, 0.f);
                float h_2 = fmaxf(acc[2] + hb, 0.f);
                float h_3 = fmaxf(acc[3] + hb, 0.f);
                qa0 += h_0 * w2a[ct]; qb0 += h_0 * w2b[ct];
                qa1 += h_1 * w2a[ct]; qb1 += h_1 * w2b[ct];
                qa2 += h_2 * w2a[ct]; qb2 += h_2 * w2b[ct];
                qa3 += h_3 * w2a[ct]; qb3 += h_3 * w2b[ct];
            }
#pragma unroll
            for (int m = 8; m; m >>= 1) {   // reduce over the 16-lane quad
                qa0 += __shfl_xor(qa0, m); qb0 += __shfl_xor(qb0, m);
                qa1 += __shfl_xor(qa1, m); qb1 += __shfl_xor(qb1, m);
                qa2 += __shfl_xor(qa2, m); qb2 += __shfl_xor(qb2, m);
                qa3 += __shfl_xor(qa3, m); qb3 += __shfl_xor(qb3, m);
            }
            int rowb = row0 + w * 16 + lq * 4;
            if (lm == 0) {
                if (rowb + 0 < n) { logits[(size_t)(rowb + 0) * 2 + 0] = qa0 + b20;
                                    logits[(size_t)(rowb + 0) * 2 + 1] = qb0 + b21; }
                if (rowb + 1 < n) { logits[(size_t)(rowb + 1) * 2 + 0] = qa1 + b20;
                                    logits[(size_t)(rowb + 1) * 2 + 1] = qb1 + b21; }
                if (rowb + 2 < n) { logits[(size_t)(rowb + 2) * 2 + 0] = qa2 + b20;
                                    logits[(size_t)(rowb + 2) * 2 + 1] = qb2 + b21; }
                if (rowb + 3 < n) { logits[(size_t)(rowb + 3) * 2 + 0] = qa3 + b20;
                                    logits[(size_t)(rowb + 3) * 2 + 1] = qb3 + b21; }
            }
        }
    }
}

// out[i,j] = sum_k x[i,k]*W[k,j] + b[j]   (x,W,b f32 -> out bf16), no relu
// (round-3 proven VALU version; named scalars, unroll bounded)
template<int F>
__global__ void proj_kernel(const float* __restrict__ x, const float* __restrict__ W,
                            const float* __restrict__ b, bf16* __restrict__ out, int n) {
    __shared__ float sW[F][64];
    __shared__ float sb[64];
    __shared__ float sx[16][F];
    int tid = threadIdx.x;
    for (int idx = tid; idx < F * 16; idx += 256)
        ((float4*)sW)[idx] = ((const float4*)W)[idx];
    if (tid < 64) sb[tid] = b[tid];
    int base = blockIdx.x * 64;
    int w = tid >> 6, j = tid & 63;
    int lw = w * 4;
    for (int g = 0; g < 4; ++g) {
        int row0 = base + g * 16;
        __syncthreads();
        for (int idx = tid; idx < 4 * F; idx += 256) {
            int rr = idx / (F / 4), c4 = idx - rr * (F / 4);
            int row = row0 + rr;
            float4 v = (row < n) ? ((const float4*)x)[(size_t)row * (F / 4) + c4]
                                 : make_float4(0.f, 0.f, 0.f, 0.f);
            *(float4*)&sx[rr][c4 * 4] = v;
        }
        __syncthreads();
        float a0 = sb[j], a1 = sb[j], a2 = sb[j], a3 = sb[j];
#pragma unroll 2
        for (int k = 0; k < F; k += 4) {
            float w0 = sW[k][j], w1 = sW[k + 1][j], w2 = sW[k + 2][j], w3 = sW[k + 3][j];
            float4 m0 = *(const float4*)&sx[lw + 0][k];
            float4 m1 = *(const float4*)&sx[lw + 1][k];
            float4 m2 = *(const float4*)&sx[lw + 2][k];
            float4 m3 = *(const float4*)&sx[lw + 3][k];
            a0 += m0.x * w0 + m0.y * w1 + m0.z * w2 + m0.w * w3;
            a1 += m1.x * w0 + m1.y * w1 + m1.z * w2 + m1.w * w3;
            a2 += m2.x * w0 + m2.y * w1 + m2.z * w2 + m2.w * w3;
            a3 += m3.x * w0 + m3.y * w1 + m3.z * w2 + m3.w * w3;
        }
        int r0 = row0 + lw;
        if (r0 + 0 < n) out[(size_t)(r0 + 0) * 64 + j] = f2b(a0);
        if (r0 + 1 < n) out[(size_t)(r0 + 1) * 64 + j] = f2b(a1);
        if (r0 + 2 < n) out[(size_t)(r0 + 2) * 64 + j] = f2b(a2);
        if (r0 + 3 < n) out[(size_t)(r0 + 3) * 64 + j] = f2b(a3);
    }
}

extern "C" void kernel_launch(void* const* d_in, const int* in_sizes, int n_in,
                              void* d_out, int out_size, void* d_ws, size_t ws_size,
                              hipStream_t stream) {
    const float* x_tx   = (const float*)d_in[0];
    const float* x_w    = (const float*)d_in[1];
    const int*   src_tw = (const int*)d_in[2];
    const int*   dst_tw = (const int*)d_in[3];
    const int*   src_wt = (const int*)d_in[4];
    const int*   dst_wt = (const int*)d_in[5];
    const float* Win_tx = (const float*)d_in[6];
    const float* bin_tx = (const float*)d_in[7];
    const float* Win_w  = (const float*)d_in[8];
    const float* bin_w  = (const float*)d_in[9];
    const float* Wl1_tw = (const float*)d_in[10];
    const float* bl1_tw = (const float*)d_in[11];
    const float* Wr1_tw = (const float*)d_in[12];
    const float* Wl1_wt = (const float*)d_in[13];
    const float* bl1_wt = (const float*)d_in[14];
    const float* Wr1_wt = (const float*)d_in[15];
    const float* Wl2_tw = (const float*)d_in[16];
    const float* bl2_tw = (const float*)d_in[17];
    const float* Wr2_tw = (const float*)d_in[18];
    const float* Wl2_wt = (const float*)d_in[19];
    const float* bl2_wt = (const float*)d_in[20];
    const float* Wr2_wt = (const float*)d_in[21];
    const float* Wh1    = (const float*)d_in[22];
    const float* bh1    = (const float*)d_in[23];
    const float* Wh2    = (const float*)d_in[24];
    const float* bh2    = (const float*)d_in[25];

    const int n_tx  = in_sizes[0] / 64;
    const int n_w   = in_sizes[1] / 32;
    const int ne_tw = in_sizes[2];
    const int ne_wt = in_sizes[4];

    // ---- workspace layout (~351 MB) ----
    bf16* mean_tx = (bf16*)d_ws;                          // n_tx*64 bf16 (128 MB)
    bf16* mean_w  = mean_tx + (size_t)n_tx * 64;          // n_w *64 bf16 ( 32 MB)
    bf16* A       = mean_w + (size_t)n_w * 64;            // n_tx*64 bf16: h_tx->t1 (in-place)
    bf16* B       = A + (size_t)n_tx * 64;                // n_w *64 bf16: h_w ->w1 (in-place)
    int*  deg_w   = (int*)(B + (size_t)n_w * 64);         // n_w
    int*  deg_tx  = deg_w + n_w;                          // n_tx
    int*  rp_w    = deg_tx + n_tx;                        // n_w
    int*  rp_tx   = rp_w + n_w;                           // n_tx
    int*  cur_w   = rp_tx + n_tx;                         // n_w  (excl scratch, then cursor)
    int*  cur_tx  = cur_w + n_w;                          // n_tx
    int*  col_tw  = cur_tx + n_tx;                        // ne_tw
    int*  col_wt  = col_tw + ne_tw;                       // ne_wt
    int*  part_w  = col_wt + ne_wt;                       // <=4096
    int*  part_tx = part_w + 4096;                        // <=4096

    float* out_logits = (float*)d_out;
    float* out_t2 = out_logits + (size_t)n_tx * 2;
    float* out_w2 = out_t2 + (size_t)n_tx * 64;

    dim3 blk(256);
    int grid_proj_tx = (n_tx + 63) / 64;
    int grid_proj_w  = (n_w + 63) / 64;
    int grid_sage_tx = (n_tx + 511) / 512;
    int grid_sage_w  = (n_w + 511) / 512;
    int grid_e_tw    = (ne_tw + 255) / 256;
    int grid_e_wt    = (ne_wt + 255) / 256;
    int grid_g_tx    = (n_tx + 3) / 4;
    int grid_g_w     = (n_w + 3) / 4;
    int np_w  = (n_w + 1023) / 1024;
    int np_tx = (n_tx + 1023) / 1024;

    // ---- CSR build (graph static: reused by conv1 AND conv2) ----
    hipMemsetAsync(deg_w, 0, (size_t)n_w * sizeof(int), stream);
    hipMemsetAsync(deg_tx, 0, (size_t)n_tx * sizeof(int), stream);
    count_int_kernel<<<grid_e_tw, blk, 0, stream>>>(dst_tw, deg_w, ne_tw);
    count_int_kernel<<<grid_e_wt, blk, 0, stream>>>(dst_wt, deg_tx, ne_wt);
    scan1_kernel<<<np_w, blk, 0, stream>>>(deg_w, cur_w, part_w, n_w);
    scan2_kernel<<<1, blk, 0, stream>>>(part_w, np_w);
    scan3_kernel<<<(n_w + 255) / 256, blk, 0, stream>>>(cur_w, part_w, rp_w, cur_w, n_w);
    scan1_kernel<<<np_tx, blk, 0, stream>>>(deg_tx, cur_tx, part_tx, n_tx);
    scan2_kernel<<<1, blk, 0, stream>>>(part_tx, np_tx);
    scan3_kernel<<<(n_tx + 255) / 256, blk, 0, stream>>>(cur_tx, part_tx, rp_tx, cur_tx, n_tx);
    scatter_kernel<<<grid_e_tw, blk, 0, stream>>>(src_tw, dst_tw, cur_w, col_tw, ne_tw);
    scatter_kernel<<<grid_e_wt, blk, 0, stream>>>(src_wt, dst_wt, cur_tx, col_wt, ne_wt);

    // ---- input projections ----
    proj_kernel<64><<<grid_proj_tx, blk, 0, stream>>>(x_tx, Win_tx, bin_tx, A, n_tx);
    proj_kernel<32><<<grid_proj_w, blk, 0, stream>>>(x_w, Win_w, bin_w, B, n_w);

    // ---- conv1: gather both means (from h_tx=A, h_w=B), then both epilogues ----
    gather_mean_kernel<<<grid_g_w, blk, 0, stream>>>(A, rp_w, deg_w, col_tw, mean_w, n_w);
    gather_mean_kernel<<<grid_g_tx, blk, 0, stream>>>(B, rp_tx, deg_tx, col_wt, mean_tx, n_tx);
    sage_mfma_kernel<false><<<grid_sage_w, blk, 0, stream>>>(
        mean_w, B, Wl1_tw, bl1_tw, Wr1_tw,
        nullptr, B, nullptr, nullptr, nullptr, nullptr, nullptr, n_w);    // w1 (in-place B)
    sage_mfma_kernel<false><<<grid_sage_tx, blk, 0, stream>>>(
        mean_tx, A, Wl1_wt, bl1_wt, Wr1_wt,
        nullptr, A, nullptr, nullptr, nullptr, nullptr, nullptr, n_tx);   // t1 (in-place A)

    // ---- conv2: gather from t1=A, w1=B, then both epilogues ----
    gather_mean_kernel<<<grid_g_w, blk, 0, stream>>>(A, rp_w, deg_w, col_tw, mean_w, n_w);
    gather_mean_kernel<<<grid_g_tx, blk, 0, stream>>>(B, rp_tx, deg_tx, col_wt, mean_tx, n_tx);
    sage_mfma_kernel<false><<<grid_sage_w, blk, 0, stream>>>(
        mean_w, B, Wl2_tw, bl2_tw, Wr2_tw,
        out_w2, nullptr, nullptr, nullptr, nullptr, nullptr, nullptr, n_w);   // w2 -> f32 out
    sage_mfma_kernel<true><<<grid_sage_tx, blk, 0, stream>>>(
        mean_tx, A, Wl2_wt, bl2_wt, Wr2_wt,
        out_t2, nullptr, Wh1, bh1, Wh2, bh2, out_logits, n_tx);               // t2 + logits
}

// Round 6
// 2049.935 us; speedup vs baseline: 21.9367x; 1.0958x over previous
//
#include <hip/hip_runtime.h>
#include <hip/hip_bf16.h>

typedef __hip_bfloat16 bf16;
typedef __attribute__((ext_vector_type(8))) short bf16x8;   // 8 bf16 = 4 VGPR
typedef __attribute__((ext_vector_type(4))) float f32x4;    // MFMA accumulator

__device__ __forceinline__ float b2f(bf16 v) { return __bfloat162float(v); }
__device__ __forceinline__ bf16 f2b(float v) { return __float2bfloat16(v); }
__device__ __forceinline__ unsigned short f2bb(float v) {   // RNE f32->bf16 bits
    unsigned int u = __float_as_uint(v);
    u += 0x7fffu + ((u >> 16) & 1u);
    return (unsigned short)(u >> 16);
}

__device__ __forceinline__ f32x4 mfma16(bf16x8 a, bf16x8 b, f32x4 c) {
    return __builtin_amdgcn_mfma_f32_16x16x32_bf16(a, b, c, 0, 0, 0);
}

// Gather a B-fragment: rows k0..k0+7 of column col from row-major W[64][64] f32.
__device__ __forceinline__ bf16x8 load_bfrag(const float* __restrict__ W, int k0, int col) {
    bf16x8 f;
#pragma unroll
    for (int j = 0; j < 8; ++j)
        f[j] = (short)f2bb(W[(size_t)(k0 + j) * 64 + col]);
    return f;
}

// Swizzled byte offsets (G4: XOR row-bits into the 16B-slot index).
__device__ __forceinline__ int swzA(int row, int b) {   // [64][128 bf16] tile, 256B rows
    return row * 256 + (b ^ ((row & 7) << 4));
}
__device__ __forceinline__ int swzH(int row, int b) {   // [64][64 bf16] tile, 128B rows
    return row * 128 + (b ^ ((row & 7) << 4));
}

// ======================= CSR build =======================
__global__ void count_int_kernel(const int* __restrict__ dst, int* __restrict__ deg, int ne) {
    int e = blockIdx.x * 256 + threadIdx.x;
    if (e < ne) atomicAdd(&deg[dst[e]], 1);
}

// block-local exclusive scan over 1024 elems (256 thr x 4); writes block totals
__global__ void scan1_kernel(const int* __restrict__ deg, int* __restrict__ excl,
                             int* __restrict__ partial, int n) {
    __shared__ int sT[256];
    int tid = threadIdx.x;
    int base = blockIdx.x * 1024 + tid * 4;
    int v0 = (base + 0 < n) ? deg[base + 0] : 0;
    int v1 = (base + 1 < n) ? deg[base + 1] : 0;
    int v2 = (base + 2 < n) ? deg[base + 2] : 0;
    int v3 = (base + 3 < n) ? deg[base + 3] : 0;
    int t = v0 + v1 + v2 + v3;
    sT[tid] = t;
    __syncthreads();
    for (int off = 1; off < 256; off <<= 1) {   // Hillis-Steele inclusive
        int x = (tid >= off) ? sT[tid - off] : 0;
        __syncthreads();
        sT[tid] += x;
        __syncthreads();
    }
    int et = sT[tid] - t;
    if (tid == 255) partial[blockIdx.x] = sT[255];
    if (base + 0 < n) excl[base + 0] = et;
    if (base + 1 < n) excl[base + 1] = et + v0;
    if (base + 2 < n) excl[base + 2] = et + v0 + v1;
    if (base + 3 < n) excl[base + 3] = et + v0 + v1 + v2;
}

// single-block exclusive scan of the partials (np <= a few thousand)
__global__ void scan2_kernel(int* __restrict__ partial, int np) {
    __shared__ int sT[256];
    __shared__ int carry;
    int tid = threadIdx.x;
    if (tid == 0) carry = 0;
    __syncthreads();
    for (int c = 0; c < np; c += 256) {
        int i = c + tid;
        int v = (i < np) ? partial[i] : 0;
        sT[tid] = v;
        __syncthreads();
        for (int off = 1; off < 256; off <<= 1) {
            int x = (tid >= off) ? sT[tid - off] : 0;
            __syncthreads();
            sT[tid] += x;
            __syncthreads();
        }
        int incl = sT[tid];
        int total = sT[255];
        if (i < np) partial[i] = carry + incl - v;
        __syncthreads();
        if (tid == 0) carry += total;
        __syncthreads();
    }
}

// rowptr[i] = cursor[i] = excl[i] + partial[i>>10]  (cursor may alias excl)
__global__ void scan3_kernel(const int* __restrict__ excl, const int* __restrict__ partial,
                             int* __restrict__ rowptr, int* __restrict__ cursor, int n) {
    int i = blockIdx.x * 256 + threadIdx.x;
    if (i < n) {
        int v = excl[i] + partial[i >> 10];
        rowptr[i] = v;
        cursor[i] = v;
    }
}

__global__ void scatter_kernel(const int* __restrict__ src, const int* __restrict__ dst,
                               int* __restrict__ cursor, int* __restrict__ col, int ne) {
    int e = blockIdx.x * 256 + threadIdx.x;
    if (e < ne) {
        int p = atomicAdd(&cursor[dst[e]], 1);
        col[p] = src[e];
    }
}

// ======================= gather mean =======================
// mean[i,:] = (1/max(deg_i,1)) * sum_{e in row i} h[col[e], :]   (bf16 out)
// One wave per dst row, lane = feature. MLP-optimized: full 8-wide blocks are
// unconditional; the remainder uses CLAMPED indices (col[min(e+k, last)]) with
// {0,1} weights so all col loads, then all row loads, issue concurrently ->
// ~2 memory latencies per row instead of deg dependent round-trips.
__global__ __launch_bounds__(256)
void gather_mean_kernel(const bf16* __restrict__ h, const int* __restrict__ rowptr,
                        const int* __restrict__ deg, const int* __restrict__ col,
                        bf16* __restrict__ mean, int n) {
    int row = blockIdx.x * 4 + (threadIdx.x >> 6);
    if (row >= n) return;
    int lane = threadIdx.x & 63;
    int base = rowptr[row];
    int d = deg[row];
    float acc = 0.f;
    int e = 0;
    for (; e + 8 <= d; e += 8) {
        int s0 = col[base + e + 0], s1 = col[base + e + 1];
        int s2 = col[base + e + 2], s3 = col[base + e + 3];
        int s4 = col[base + e + 4], s5 = col[base + e + 5];
        int s6 = col[base + e + 6], s7 = col[base + e + 7];
        acc += b2f(h[(size_t)s0 * 64 + lane]) + b2f(h[(size_t)s1 * 64 + lane])
             + b2f(h[(size_t)s2 * 64 + lane]) + b2f(h[(size_t)s3 * 64 + lane])
             + b2f(h[(size_t)s4 * 64 + lane]) + b2f(h[(size_t)s5 * 64 + lane])
             + b2f(h[(size_t)s6 * 64 + lane]) + b2f(h[(size_t)s7 * 64 + lane]);
    }
    int rem = d - e;
    if (rem > 0) {
        int last = base + d - 1;
        int i0 = base + e;
        int j1 = i0 + 1 < last ? i0 + 1 : last;
        int j2 = i0 + 2 < last ? i0 + 2 : last;
        int j3 = i0 + 3 < last ? i0 + 3 : last;
        int j4 = i0 + 4 < last ? i0 + 4 : last;
        int j5 = i0 + 5 < last ? i0 + 5 : last;
        int j6 = i0 + 6 < last ? i0 + 6 : last;
        int j7 = i0 + 7 < last ? i0 + 7 : last;
        int s0 = col[i0], s1 = col[j1], s2 = col[j2], s3 = col[j3];
        int s4 = col[j4], s5 = col[j5], s6 = col[j6], s7 = col[j7];
        float w1 = rem > 1 ? 1.f : 0.f, w2 = rem > 2 ? 1.f : 0.f;
        float w3 = rem > 3 ? 1.f : 0.f, w4 = rem > 4 ? 1.f : 0.f;
        float w5 = rem > 5 ? 1.f : 0.f, w6 = rem > 6 ? 1.f : 0.f;
        float w7 = rem > 7 ? 1.f : 0.f;
        acc += b2f(h[(size_t)s0 * 64 + lane])
             + w1 * b2f(h[(size_t)s1 * 64 + lane])
             + w2 * b2f(h[(size_t)s2 * 64 + lane])
             + w3 * b2f(h[(size_t)s3 * 64 + lane])
             + w4 * b2f(h[(size_t)s4 * 64 + lane])
             + w5 * b2f(h[(size_t)s5 * 64 + lane])
             + w6 * b2f(h[(size_t)s6 * 64 + lane])
             + w7 * b2f(h[(size_t)s7 * 64 + lane]);
    }
    float m = acc / fmaxf((float)d, 1.f);
    mean[(size_t)row * 64 + lane] = f2b(m);
}

// ======================= input projection, F=64 (MFMA) =======================
// out[i,j] = x[i,:] . W[:,j] + b[j]  (no relu). Same tiling as sage_mfma:
// A = x (f32 -> bf16, swizzled [64][64] LDS tile), B = Win register fragments,
// K=64 -> 2 MFMAs per 16-col tile. Block covers 512 rows.
__global__ __launch_bounds__(256)
void proj64_mfma_kernel(const float* __restrict__ x, const float* __restrict__ W,
                        const float* __restrict__ b, bf16* __restrict__ out, int n) {
    __shared__ __align__(16) short sP[64 * 64];   // 8 KB
    int tid = threadIdx.x;
    int lane = tid & 63, w = tid >> 6;
    int lm = lane & 15, lq = lane >> 4;

    bf16x8 wc[4][2];
    float bv[4];
#pragma unroll
    for (int ct = 0; ct < 4; ++ct) {
        int colc = ct * 16 + lm;
        wc[ct][0] = load_bfrag(W, lq * 8, colc);
        wc[ct][1] = load_bfrag(W, 32 + lq * 8, colc);
        bv[ct] = b[colc];
    }

    const float4* x4 = (const float4*)x;
    for (int g = 0; g < 8; ++g) {
        int row0 = blockIdx.x * 512 + g * 64;
        if (row0 >= n) break;
        __syncthreads();
        // stage 64 rows of x: f32 float4 -> 8B bf16 granule, swizzled
#pragma unroll
        for (int i = 0; i < 4; ++i) {
            int idx = tid + i * 256;             // 0..1023
            int row = idx >> 4, g4 = idx & 15;   // 16 float4-granules per row
            int grow = row0 + row;
            float4 v = make_float4(0.f, 0.f, 0.f, 0.f);
            if (grow < n) v = x4[(size_t)grow * 16 + g4];
            ushort4 p;
            p.x = f2bb(v.x); p.y = f2bb(v.y); p.z = f2bb(v.z); p.w = f2bb(v.w);
            *(ushort4*)((char*)sP + swzH(row, g4 * 8)) = p;
        }
        __syncthreads();

        int arow = w * 16 + lm;
        bf16x8 a0 = *(const bf16x8*)((char*)sP + swzH(arow, lq * 16));
        bf16x8 a1 = *(const bf16x8*)((char*)sP + swzH(arow, 64 + lq * 16));
#pragma unroll
        for (int ct = 0; ct < 4; ++ct) {
            f32x4 acc = {0.f, 0.f, 0.f, 0.f};
            acc = mfma16(a0, wc[ct][0], acc);
            acc = mfma16(a1, wc[ct][1], acc);
            int colc = ct * 16 + lm;
#pragma unroll
            for (int r = 0; r < 4; ++r) {
                int grow = row0 + w * 16 + lq * 4 + r;
                if (grow < n)
                    out[(size_t)grow * 64 + colc] = f2b(acc[r] + bv[ct]);
            }
        }
    }
}

// ======================= SAGE epilogue (MFMA) =======================
// out[i,j] = relu( mean[i,:] . Wl[:,j] + bl[j] + xd[i,:] . Wr[:,j] )
// One K=128 GEMM: A = [mean | xd] (bf16, swizzled LDS), B = [Wl ; Wr] (bf16
// register fragments, loaded once per block). Wave w owns rows w*16..w*16+15
// of each 64-row group; block covers 512 rows. C/D: col=lane&15,
// row=(lane>>4)*4+reg. In-place outb==xd safe (staged, synced, overwritten).
// HEAD: t2 restaged bf16 wave-locally into sH, K=64 MFMA GEMM, 16-lane
// shfl_xor reduce for the 64->2 contraction.
template<bool HEAD>
__global__ __launch_bounds__(256, 2)
void sage_mfma_kernel(const bf16* __restrict__ mean, const bf16* __restrict__ xd,
                      const float* __restrict__ Wl, const float* __restrict__ bl,
                      const float* __restrict__ Wr,
                      float* __restrict__ outf, bf16* __restrict__ outb,
                      const float* __restrict__ Wh1, const float* __restrict__ bh1,
                      const float* __restrict__ Wh2, const float* __restrict__ bh2,
                      float* __restrict__ logits, int n) {
    __shared__ __align__(16) short sA[64 * 128];              // 16 KB
    __shared__ __align__(16) short sH[HEAD ? 64 * 64 : 8];    // 8 KB (HEAD)
    int tid = threadIdx.x;
    int lane = tid & 63, w = tid >> 6;
    int lm = lane & 15, lq = lane >> 4;

    // --- weight fragments: once per block, held in registers ---
    bf16x8 wc[4][4];   // [col-tile][k-step]; ks 0,1 = Wl(k0=0,32), ks 2,3 = Wr
    bf16x8 wh[4][2];
    float blv[4], h1v[4], w2a[4], w2b[4];
#pragma unroll
    for (int ct = 0; ct < 4; ++ct) {
        int col = ct * 16 + lm;
        wc[ct][0] = load_bfrag(Wl, lq * 8, col);
        wc[ct][1] = load_bfrag(Wl, 32 + lq * 8, col);
        wc[ct][2] = load_bfrag(Wr, lq * 8, col);
        wc[ct][3] = load_bfrag(Wr, 32 + lq * 8, col);
        blv[ct] = bl[col];
        if (HEAD) {
            wh[ct][0] = load_bfrag(Wh1, lq * 8, col);
            wh[ct][1] = load_bfrag(Wh1, 32 + lq * 8, col);
            h1v[ct] = bh1[col];
            w2a[ct] = Wh2[col * 2 + 0];
            w2b[ct] = Wh2[col * 2 + 1];
        }
    }
    float b20 = 0.f, b21 = 0.f;
    if (HEAD) { b20 = bh2[0]; b21 = bh2[1]; }

    const bf16x8* mean8 = (const bf16x8*)mean;
    const bf16x8* xd8   = (const bf16x8*)xd;

    for (int g = 0; g < 8; ++g) {
        int row0 = blockIdx.x * 512 + g * 64;
        if (row0 >= n) break;
        __syncthreads();   // protect sA reuse (prev group's fragment reads done)
        // stage mean -> cols 0..63, xd -> cols 64..127 (16B granules, 2/thread each)
#pragma unroll
        for (int i = 0; i < 2; ++i) {
            int idx = tid + i * 256;             // 0..511
            int row = idx >> 3, c8 = idx & 7;    // 8x16B per 64-col row
            int grow = row0 + row;
            bf16x8 m, u;
#pragma unroll
            for (int j = 0; j < 8; ++j) { m[j] = 0; u[j] = 0; }
            if (grow < n) {
                m = mean8[(size_t)grow * 8 + c8];
                u = xd8[(size_t)grow * 8 + c8];
            }
            *(bf16x8*)((char*)sA + swzA(row, c8 * 16)) = m;
            *(bf16x8*)((char*)sA + swzA(row, 128 + c8 * 16)) = u;
        }
        __syncthreads();

        // --- compute: wave w owns rows w*16..w*16+15 ---
        int arow = w * 16 + lm;
        bf16x8 a0 = *(const bf16x8*)((char*)sA + swzA(arow, lq * 16));
        bf16x8 a1 = *(const bf16x8*)((char*)sA + swzA(arow, 64 + lq * 16));
        bf16x8 a2 = *(const bf16x8*)((char*)sA + swzA(arow, 128 + lq * 16));
        bf16x8 a3 = *(const bf16x8*)((char*)sA + swzA(arow, 192 + lq * 16));
#pragma unroll
        for (int ct = 0; ct < 4; ++ct) {
            f32x4 acc = {0.f, 0.f, 0.f, 0.f};
            acc = mfma16(a0, wc[ct][0], acc);
            acc = mfma16(a1, wc[ct][1], acc);
            acc = mfma16(a2, wc[ct][2], acc);
            acc = mfma16(a3, wc[ct][3], acc);
            int col = ct * 16 + lm;
#pragma unroll
            for (int r = 0; r < 4; ++r) {
                int lrow = w * 16 + lq * 4 + r;
                int grow = row0 + lrow;
                float v = fmaxf(acc[r] + blv[ct], 0.f);
                if (grow < n) {
                    if (outf) outf[(size_t)grow * 64 + col] = v;
                    if (outb) outb[(size_t)grow * 64 + col] = f2b(v);
                }
                if (HEAD)   // wave-local restage; same wave reads below
                    *(short*)((char*)sH + swzH(lrow, col * 2)) = (short)f2bb(v);
            }
        }
        if (HEAD) {
            bf16x8 h0 = *(const bf16x8*)((char*)sH + swzH(arow, lq * 16));
            bf16x8 h1 = *(const bf16x8*)((char*)sH + swzH(arow, 64 + lq * 16));
            float qa0 = 0.f, qa1 = 0.f, qa2 = 0.f, qa3 = 0.f;
            float qb0 = 0.f, qb1 = 0.f, qb2 = 0.f, qb3 = 0.f;
#pragma unroll
            for (int ct = 0; ct < 4; ++ct) {
                f32x4 acc = {0.f, 0.f, 0.f, 0.f};
                acc = mfma16(h0, wh[ct][0], acc);
                acc = mfma16(h1, wh[ct][1], acc);
                float hb = h1v[ct];
                float h_0 = fmaxf(acc[0] + hb, 0.f);
                float h_1 = fmaxf(acc[1] + hb, 0.f);
                float h_2 = fmaxf(acc[2] + hb, 0.f);
                float h_3 = fmaxf(acc[3] + hb, 0.f);
                qa0 += h_0 * w2a[ct]; qb0 += h_0 * w2b[ct];
                qa1 += h_1 * w2a[ct]; qb1 += h_1 * w2b[ct];
                qa2 += h_2 * w2a[ct]; qb2 += h_2 * w2b[ct];
                qa3 += h_3 * w2a[ct]; qb3 += h_3 * w2b[ct];
            }
#pragma unroll
            for (int m = 8; m; m >>= 1) {   // reduce over the 16-lane quad
                qa0 += __shfl_xor(qa0, m); qb0 += __shfl_xor(qb0, m);
                qa1 += __shfl_xor(qa1, m); qb1 += __shfl_xor(qb1, m);
                qa2 += __shfl_xor(qa2, m); qb2 += __shfl_xor(qb2, m);
                qa3 += __shfl_xor(qa3, m); qb3 += __shfl_xor(qb3, m);
            }
            int rowb = row0 + w * 16 + lq * 4;
            if (lm == 0) {
                if (rowb + 0 < n) { logits[(size_t)(rowb + 0) * 2 + 0] = qa0 + b20;
                                    logits[(size_t)(rowb + 0) * 2 + 1] = qb0 + b21; }
                if (rowb + 1 < n) { logits[(size_t)(rowb + 1) * 2 + 0] = qa1 + b20;
                                    logits[(size_t)(rowb + 1) * 2 + 1] = qb1 + b21; }
                if (rowb + 2 < n) { logits[(size_t)(rowb + 2) * 2 + 0] = qa2 + b20;
                                    logits[(size_t)(rowb + 2) * 2 + 1] = qb2 + b21; }
                if (rowb + 3 < n) { logits[(size_t)(rowb + 3) * 2 + 0] = qa3 + b20;
                                    logits[(size_t)(rowb + 3) * 2 + 1] = qb3 + b21; }
            }
        }
    }
}

// out[i,j] = sum_k x[i,k]*W[k,j] + b[j]   (x,W,b f32 -> out bf16), no relu
// (VALU version, used only for the small F=32 projection)
template<int F>
__global__ void proj_kernel(const float* __restrict__ x, const float* __restrict__ W,
                            const float* __restrict__ b, bf16* __restrict__ out, int n) {
    __shared__ float sW[F][64];
    __shared__ float sb[64];
    __shared__ float sx[16][F];
    int tid = threadIdx.x;
    for (int idx = tid; idx < F * 16; idx += 256)
        ((float4*)sW)[idx] = ((const float4*)W)[idx];
    if (tid < 64) sb[tid] = b[tid];
    int base = blockIdx.x * 64;
    int w = tid >> 6, j = tid & 63;
    int lw = w * 4;
    for (int g = 0; g < 4; ++g) {
        int row0 = base + g * 16;
        __syncthreads();
        for (int idx = tid; idx < 4 * F; idx += 256) {
            int rr = idx / (F / 4), c4 = idx - rr * (F / 4);
            int row = row0 + rr;
            float4 v = (row < n) ? ((const float4*)x)[(size_t)row * (F / 4) + c4]
                                 : make_float4(0.f, 0.f, 0.f, 0.f);
            *(float4*)&sx[rr][c4 * 4] = v;
        }
        __syncthreads();
        float a0 = sb[j], a1 = sb[j], a2 = sb[j], a3 = sb[j];
#pragma unroll 2
        for (int k = 0; k < F; k += 4) {
            float w0 = sW[k][j], w1 = sW[k + 1][j], w2 = sW[k + 2][j], w3 = sW[k + 3][j];
            float4 m0 = *(const float4*)&sx[lw + 0][k];
            float4 m1 = *(const float4*)&sx[lw + 1][k];
            float4 m2 = *(const float4*)&sx[lw + 2][k];
            float4 m3 = *(const float4*)&sx[lw + 3][k];
            a0 += m0.x * w0 + m0.y * w1 + m0.z * w2 + m0.w * w3;
            a1 += m1.x * w0 + m1.y * w1 + m1.z * w2 + m1.w * w3;
            a2 += m2.x * w0 + m2.y * w1 + m2.z * w2 + m2.w * w3;
            a3 += m3.x * w0 + m3.y * w1 + m3.z * w2 + m3.w * w3;
        }
        int r0 = row0 + lw;
        if (r0 + 0 < n) out[(size_t)(r0 + 0) * 64 + j] = f2b(a0);
        if (r0 + 1 < n) out[(size_t)(r0 + 1) * 64 + j] = f2b(a1);
        if (r0 + 2 < n) out[(size_t)(r0 + 2) * 64 + j] = f2b(a2);
        if (r0 + 3 < n) out[(size_t)(r0 + 3) * 64 + j] = f2b(a3);
    }
}

extern "C" void kernel_launch(void* const* d_in, const int* in_sizes, int n_in,
                              void* d_out, int out_size, void* d_ws, size_t ws_size,
                              hipStream_t stream) {
    const float* x_tx   = (const float*)d_in[0];
    const float* x_w    = (const float*)d_in[1];
    const int*   src_tw = (const int*)d_in[2];
    const int*   dst_tw = (const int*)d_in[3];
    const int*   src_wt = (const int*)d_in[4];
    const int*   dst_wt = (const int*)d_in[5];
    const float* Win_tx = (const float*)d_in[6];
    const float* bin_tx = (const float*)d_in[7];
    const float* Win_w  = (const float*)d_in[8];
    const float* bin_w  = (const float*)d_in[9];
    const float* Wl1_tw = (const float*)d_in[10];
    const float* bl1_tw = (const float*)d_in[11];
    const float* Wr1_tw = (const float*)d_in[12];
    const float* Wl1_wt = (const float*)d_in[13];
    const float* bl1_wt = (const float*)d_in[14];
    const float* Wr1_wt = (const float*)d_in[15];
    const float* Wl2_tw = (const float*)d_in[16];
    const float* bl2_tw = (const float*)d_in[17];
    const float* Wr2_tw = (const float*)d_in[18];
    const float* Wl2_wt = (const float*)d_in[19];
    const float* bl2_wt = (const float*)d_in[20];
    const float* Wr2_wt = (const float*)d_in[21];
    const float* Wh1    = (const float*)d_in[22];
    const float* bh1    = (const float*)d_in[23];
    const float* Wh2    = (const float*)d_in[24];
    const float* bh2    = (const float*)d_in[25];

    const int n_tx  = in_sizes[0] / 64;
    const int n_w   = in_sizes[1] / 32;
    const int ne_tw = in_sizes[2];
    const int ne_wt = in_sizes[4];

    // ---- workspace layout (~351 MB) ----
    bf16* mean_tx = (bf16*)d_ws;                          // n_tx*64 bf16 (128 MB)
    bf16* mean_w  = mean_tx + (size_t)n_tx * 64;          // n_w *64 bf16 ( 32 MB)
    bf16* A       = mean_w + (size_t)n_w * 64;            // n_tx*64 bf16: h_tx->t1 (in-place)
    bf16* B       = A + (size_t)n_tx * 64;                // n_w *64 bf16: h_w ->w1 (in-place)
    int*  deg_w   = (int*)(B + (size_t)n_w * 64);         // n_w
    int*  deg_tx  = deg_w + n_w;                          // n_tx
    int*  rp_w    = deg_tx + n_tx;                        // n_w
    int*  rp_tx   = rp_w + n_w;                           // n_tx
    int*  cur_w   = rp_tx + n_tx;                         // n_w  (excl scratch, then cursor)
    int*  cur_tx  = cur_w + n_w;                          // n_tx
    int*  col_tw  = cur_tx + n_tx;                        // ne_tw
    int*  col_wt  = col_tw + ne_tw;                       // ne_wt
    int*  part_w  = col_wt + ne_wt;                       // <=4096
    int*  part_tx = part_w + 4096;                        // <=4096

    float* out_logits = (float*)d_out;
    float* out_t2 = out_logits + (size_t)n_tx * 2;
    float* out_w2 = out_t2 + (size_t)n_tx * 64;

    dim3 blk(256);
    int grid_proj_tx = (n_tx + 511) / 512;
    int grid_proj_w  = (n_w + 63) / 64;
    int grid_sage_tx = (n_tx + 511) / 512;
    int grid_sage_w  = (n_w + 511) / 512;
    int grid_e_tw    = (ne_tw + 255) / 256;
    int grid_e_wt    = (ne_wt + 255) / 256;
    int grid_g_tx    = (n_tx + 3) / 4;
    int grid_g_w     = (n_w + 3) / 4;
    int np_w  = (n_w + 1023) / 1024;
    int np_tx = (n_tx + 1023) / 1024;

    // ---- CSR build (graph static: reused by conv1 AND conv2) ----
    hipMemsetAsync(deg_w, 0, (size_t)n_w * sizeof(int), stream);
    hipMemsetAsync(deg_tx, 0, (size_t)n_tx * sizeof(int), stream);
    count_int_kernel<<<grid_e_tw, blk, 0, stream>>>(dst_tw, deg_w, ne_tw);
    count_int_kernel<<<grid_e_wt, blk, 0, stream>>>(dst_wt, deg_tx, ne_wt);
    scan1_kernel<<<np_w, blk, 0, stream>>>(deg_w, cur_w, part_w, n_w);
    scan2_kernel<<<1, blk, 0, stream>>>(part_w, np_w);
    scan3_kernel<<<(n_w + 255) / 256, blk, 0, stream>>>(cur_w, part_w, rp_w, cur_w, n_w);
    scan1_kernel<<<np_tx, blk, 0, stream>>>(deg_tx, cur_tx, part_tx, n_tx);
    scan2_kernel<<<1, blk, 0, stream>>>(part_tx, np_tx);
    scan3_kernel<<<(n_tx + 255) / 256, blk, 0, stream>>>(cur_tx, part_tx, rp_tx, cur_tx, n_tx);
    scatter_kernel<<<grid_e_tw, blk, 0, stream>>>(src_tw, dst_tw, cur_w, col_tw, ne_tw);
    scatter_kernel<<<grid_e_wt, blk, 0, stream>>>(src_wt, dst_wt, cur_tx, col_wt, ne_wt);

    // ---- input projections ----
    proj64_mfma_kernel<<<grid_proj_tx, blk, 0, stream>>>(x_tx, Win_tx, bin_tx, A, n_tx);
    proj_kernel<32><<<grid_proj_w, blk, 0, stream>>>(x_w, Win_w, bin_w, B, n_w);

    // ---- conv1: gather both means (from h_tx=A, h_w=B), then both epilogues ----
    gather_mean_kernel<<<grid_g_w, blk, 0, stream>>>(A, rp_w, deg_w, col_tw, mean_w, n_w);
    gather_mean_kernel<<<grid_g_tx, blk, 0, stream>>>(B, rp_tx, deg_tx, col_wt, mean_tx, n_tx);
    sage_mfma_kernel<false><<<grid_sage_w, blk, 0, stream>>>(
        mean_w, B, Wl1_tw, bl1_tw, Wr1_tw,
        nullptr, B, nullptr, nullptr, nullptr, nullptr, nullptr, n_w);    // w1 (in-place B)
    sage_mfma_kernel<false><<<grid_sage_tx, blk, 0, stream>>>(
        mean_tx, A, Wl1_wt, bl1_wt, Wr1_wt,
        nullptr, A, nullptr, nullptr, nullptr, nullptr, nullptr, n_tx);   // t1 (in-place A)

    // ---- conv2: gather from t1=A, w1=B, then both epilogues ----
    gather_mean_kernel<<<grid_g_w, blk, 0, stream>>>(A, rp_w, deg_w, col_tw, mean_w, n_w);
    gather_mean_kernel<<<grid_g_tx, blk, 0, stream>>>(B, rp_tx, deg_tx, col_wt, mean_tx, n_tx);
    sage_mfma_kernel<false><<<grid_sage_w, blk, 0, stream>>>(
        mean_w, B, Wl2_tw, bl2_tw, Wr2_tw,
        out_w2, nullptr, nullptr, nullptr, nullptr, nullptr, nullptr, n_w);   // w2 -> f32 out
    sage_mfma_kernel<true><<<grid_sage_tx, blk, 0, stream>>>(
        mean_tx, A, Wl2_wt, bl2_wt, Wr2_wt,
        out_t2, nullptr, Wh1, bh1, Wh2, bh2, out_logits, n_tx);               // t2 + logits
}

// Round 7
// 1633.089 us; speedup vs baseline: 27.5361x; 1.2553x over previous
//
#include <hip/hip_runtime.h>
#include <hip/hip_bf16.h>

typedef __hip_bfloat16 bf16;
typedef __attribute__((ext_vector_type(8))) short bf16x8;   // 8 bf16 = 4 VGPR
typedef __attribute__((ext_vector_type(4))) float f32x4;    // MFMA accumulator

__device__ __forceinline__ float b2f(bf16 v) { return __bfloat162float(v); }
__device__ __forceinline__ bf16 f2b(float v) { return __float2bfloat16(v); }
__device__ __forceinline__ unsigned short f2bb(float v) {   // RNE f32->bf16 bits
    unsigned int u = __float_as_uint(v);
    u += 0x7fffu + ((u >> 16) & 1u);
    return (unsigned short)(u >> 16);
}
// bf16x8 element k (compile-time k) -> f32 via bit shift
__device__ __forceinline__ float b2fx(bf16x8 v, int k) {
    return __uint_as_float(((unsigned int)(unsigned short)v[k]) << 16);
}

__device__ __forceinline__ f32x4 mfma16(bf16x8 a, bf16x8 b, f32x4 c) {
    return __builtin_amdgcn_mfma_f32_16x16x32_bf16(a, b, c, 0, 0, 0);
}

// Gather a B-fragment: rows k0..k0+7 of column col from row-major W[64][64] f32.
__device__ __forceinline__ bf16x8 load_bfrag(const float* __restrict__ W, int k0, int col) {
    bf16x8 f;
#pragma unroll
    for (int j = 0; j < 8; ++j)
        f[j] = (short)f2bb(W[(size_t)(k0 + j) * 64 + col]);
    return f;
}

// Swizzled byte offsets (G4: XOR row-bits into the 16B-slot index).
__device__ __forceinline__ int swzA(int row, int b) {   // [64][128 bf16] tile, 256B rows
    return row * 256 + (b ^ ((row & 7) << 4));
}
__device__ __forceinline__ int swzH(int row, int b) {   // [64][64 bf16] tile, 128B rows
    return row * 128 + (b ^ ((row & 7) << 4));
}

// ======================= CSR build =======================
__global__ void count_int_kernel(const int* __restrict__ dst, int* __restrict__ deg, int ne) {
    int e = blockIdx.x * 256 + threadIdx.x;
    if (e < ne) atomicAdd(&deg[dst[e]], 1);
}

// block-local exclusive scan over 1024 elems (256 thr x 4); writes block totals
__global__ void scan1_kernel(const int* __restrict__ deg, int* __restrict__ excl,
                             int* __restrict__ partial, int n) {
    __shared__ int sT[256];
    int tid = threadIdx.x;
    int base = blockIdx.x * 1024 + tid * 4;
    int v0 = (base + 0 < n) ? deg[base + 0] : 0;
    int v1 = (base + 1 < n) ? deg[base + 1] : 0;
    int v2 = (base + 2 < n) ? deg[base + 2] : 0;
    int v3 = (base + 3 < n) ? deg[base + 3] : 0;
    int t = v0 + v1 + v2 + v3;
    sT[tid] = t;
    __syncthreads();
    for (int off = 1; off < 256; off <<= 1) {   // Hillis-Steele inclusive
        int x = (tid >= off) ? sT[tid - off] : 0;
        __syncthreads();
        sT[tid] += x;
        __syncthreads();
    }
    int et = sT[tid] - t;
    if (tid == 255) partial[blockIdx.x] = sT[255];
    if (base + 0 < n) excl[base + 0] = et;
    if (base + 1 < n) excl[base + 1] = et + v0;
    if (base + 2 < n) excl[base + 2] = et + v0 + v1;
    if (base + 3 < n) excl[base + 3] = et + v0 + v1 + v2;
}

// single-block exclusive scan of the partials (np <= a few thousand)
__global__ void scan2_kernel(int* __restrict__ partial, int np) {
    __shared__ int sT[256];
    __shared__ int carry;
    int tid = threadIdx.x;
    if (tid == 0) carry = 0;
    __syncthreads();
    for (int c = 0; c < np; c += 256) {
        int i = c + tid;
        int v = (i < np) ? partial[i] : 0;
        sT[tid] = v;
        __syncthreads();
        for (int off = 1; off < 256; off <<= 1) {
            int x = (tid >= off) ? sT[tid - off] : 0;
            __syncthreads();
            sT[tid] += x;
            __syncthreads();
        }
        int incl = sT[tid];
        int total = sT[255];
        if (i < np) partial[i] = carry + incl - v;
        __syncthreads();
        if (tid == 0) carry += total;
        __syncthreads();
    }
}

// rowptr[i] = cursor[i] = excl[i] + partial[i>>10]  (cursor may alias excl)
__global__ void scan3_kernel(const int* __restrict__ excl, const int* __restrict__ partial,
                             int* __restrict__ rowptr, int* __restrict__ cursor, int n) {
    int i = blockIdx.x * 256 + threadIdx.x;
    if (i < n) {
        int v = excl[i] + partial[i >> 10];
        rowptr[i] = v;
        cursor[i] = v;
    }
}

__global__ void scatter_kernel(const int* __restrict__ src, const int* __restrict__ dst,
                               int* __restrict__ cursor, int* __restrict__ col, int ne) {
    int e = blockIdx.x * 256 + threadIdx.x;
    if (e < ne) {
        int p = atomicAdd(&cursor[dst[e]], 1);
        col[p] = src[e];
    }
}

// ======================= gather mean =======================
// mean[i,:] = (1/max(deg_i,1)) * sum_{e in row i} h[col[e], :]   (bf16 out)
// Wave repack: 8 rows/wave, 8 lanes/row, 8 features/lane. Each lane loads a
// 16B bf16x8 per edge slot (64 lanes x 16B = 1KB/instruction, coalescing sweet
// spot) instead of round-6's 2B scalar per lane -> ~8x fewer VALU instructions
// per row. 8-slot chunks with clamped indices + {0,1} weights preserve the
// EXACT f32 summation order and per-feature a/d divide of prior rounds
// (bit-identical output). d=0 rows skip the loop (no OOB).
#define GM_ACC(x, w) \
    a0 += (w) * b2fx(x, 0); a1 += (w) * b2fx(x, 1); \
    a2 += (w) * b2fx(x, 2); a3 += (w) * b2fx(x, 3); \
    a4 += (w) * b2fx(x, 4); a5 += (w) * b2fx(x, 5); \
    a6 += (w) * b2fx(x, 6); a7 += (w) * b2fx(x, 7);

__global__ __launch_bounds__(256)
void gather_mean_kernel(const bf16* __restrict__ h, const int* __restrict__ rowptr,
                        const int* __restrict__ deg, const int* __restrict__ col,
                        bf16* __restrict__ mean, int n) {
    int tid = threadIdx.x;
    int row = blockIdx.x * 32 + (tid >> 3);   // 32 rows per block, 8 lanes each
    if (row >= n) return;
    int fg = tid & 7;                         // feature octet: cols fg*8..fg*8+7
    int base = rowptr[row];
    int d = deg[row];
    int lasto = (d > 0) ? d - 1 : 0;
    float a0 = 0.f, a1 = 0.f, a2 = 0.f, a3 = 0.f;
    float a4 = 0.f, a5 = 0.f, a6 = 0.f, a7 = 0.f;
    for (int e0 = 0; e0 < d; e0 += 8) {
        int o1 = (e0 + 1 < d) ? e0 + 1 : lasto;
        int o2 = (e0 + 2 < d) ? e0 + 2 : lasto;
        int o3 = (e0 + 3 < d) ? e0 + 3 : lasto;
        int o4 = (e0 + 4 < d) ? e0 + 4 : lasto;
        int o5 = (e0 + 5 < d) ? e0 + 5 : lasto;
        int o6 = (e0 + 6 < d) ? e0 + 6 : lasto;
        int o7 = (e0 + 7 < d) ? e0 + 7 : lasto;
        int s0 = col[base + e0], s1 = col[base + o1];
        int s2 = col[base + o2], s3 = col[base + o3];
        int s4 = col[base + o4], s5 = col[base + o5];
        int s6 = col[base + o6], s7 = col[base + o7];
        bf16x8 x0 = *(const bf16x8*)(h + ((size_t)s0 << 6) + (fg << 3));
        bf16x8 x1 = *(const bf16x8*)(h + ((size_t)s1 << 6) + (fg << 3));
        bf16x8 x2 = *(const bf16x8*)(h + ((size_t)s2 << 6) + (fg << 3));
        bf16x8 x3 = *(const bf16x8*)(h + ((size_t)s3 << 6) + (fg << 3));
        bf16x8 x4 = *(const bf16x8*)(h + ((size_t)s4 << 6) + (fg << 3));
        bf16x8 x5 = *(const bf16x8*)(h + ((size_t)s5 << 6) + (fg << 3));
        bf16x8 x6 = *(const bf16x8*)(h + ((size_t)s6 << 6) + (fg << 3));
        bf16x8 x7 = *(const bf16x8*)(h + ((size_t)s7 << 6) + (fg << 3));
        float w1 = (e0 + 1 < d) ? 1.f : 0.f;
        float w2 = (e0 + 2 < d) ? 1.f : 0.f;
        float w3 = (e0 + 3 < d) ? 1.f : 0.f;
        float w4 = (e0 + 4 < d) ? 1.f : 0.f;
        float w5 = (e0 + 5 < d) ? 1.f : 0.f;
        float w6 = (e0 + 6 < d) ? 1.f : 0.f;
        float w7 = (e0 + 7 < d) ? 1.f : 0.f;
        GM_ACC(x0, 1.f)
        GM_ACC(x1, w1)
        GM_ACC(x2, w2)
        GM_ACC(x3, w3)
        GM_ACC(x4, w4)
        GM_ACC(x5, w5)
        GM_ACC(x6, w6)
        GM_ACC(x7, w7)
    }
    float dd = fmaxf((float)d, 1.f);
    bf16x8 o;
    o[0] = (short)f2bb(a0 / dd); o[1] = (short)f2bb(a1 / dd);
    o[2] = (short)f2bb(a2 / dd); o[3] = (short)f2bb(a3 / dd);
    o[4] = (short)f2bb(a4 / dd); o[5] = (short)f2bb(a5 / dd);
    o[6] = (short)f2bb(a6 / dd); o[7] = (short)f2bb(a7 / dd);
    *(bf16x8*)(mean + ((size_t)row << 6) + (fg << 3)) = o;
}

// ======================= input projection, F=64 (MFMA) =======================
// out[i,j] = x[i,:] . W[:,j] + b[j]  (no relu). Same tiling as sage_mfma:
// A = x (f32 -> bf16, swizzled [64][64] LDS tile), B = Win register fragments,
// K=64 -> 2 MFMAs per 16-col tile. Block covers 512 rows.
__global__ __launch_bounds__(256)
void proj64_mfma_kernel(const float* __restrict__ x, const float* __restrict__ W,
                        const float* __restrict__ b, bf16* __restrict__ out, int n) {
    __shared__ __align__(16) short sP[64 * 64];   // 8 KB
    int tid = threadIdx.x;
    int lane = tid & 63, w = tid >> 6;
    int lm = lane & 15, lq = lane >> 4;

    bf16x8 wc[4][2];
    float bv[4];
#pragma unroll
    for (int ct = 0; ct < 4; ++ct) {
        int colc = ct * 16 + lm;
        wc[ct][0] = load_bfrag(W, lq * 8, colc);
        wc[ct][1] = load_bfrag(W, 32 + lq * 8, colc);
        bv[ct] = b[colc];
    }

    const float4* x4 = (const float4*)x;
    for (int g = 0; g < 8; ++g) {
        int row0 = blockIdx.x * 512 + g * 64;
        if (row0 >= n) break;
        __syncthreads();
        // stage 64 rows of x: f32 float4 -> 8B bf16 granule, swizzled
#pragma unroll
        for (int i = 0; i < 4; ++i) {
            int idx = tid + i * 256;             // 0..1023
            int row = idx >> 4, g4 = idx & 15;   // 16 float4-granules per row
            int grow = row0 + row;
            float4 v = make_float4(0.f, 0.f, 0.f, 0.f);
            if (grow < n) v = x4[(size_t)grow * 16 + g4];
            ushort4 p;
            p.x = f2bb(v.x); p.y = f2bb(v.y); p.z = f2bb(v.z); p.w = f2bb(v.w);
            *(ushort4*)((char*)sP + swzH(row, g4 * 8)) = p;
        }
        __syncthreads();

        int arow = w * 16 + lm;
        bf16x8 a0 = *(const bf16x8*)((char*)sP + swzH(arow, lq * 16));
        bf16x8 a1 = *(const bf16x8*)((char*)sP + swzH(arow, 64 + lq * 16));
#pragma unroll
        for (int ct = 0; ct < 4; ++ct) {
            f32x4 acc = {0.f, 0.f, 0.f, 0.f};
            acc = mfma16(a0, wc[ct][0], acc);
            acc = mfma16(a1, wc[ct][1], acc);
            int colc = ct * 16 + lm;
#pragma unroll
            for (int r = 0; r < 4; ++r) {
                int grow = row0 + w * 16 + lq * 4 + r;
                if (grow < n)
                    out[(size_t)grow * 64 + colc] = f2b(acc[r] + bv[ct]);
            }
        }
    }
}

// ======================= SAGE epilogue (MFMA) =======================
// out[i,j] = relu( mean[i,:] . Wl[:,j] + bl[j] + xd[i,:] . Wr[:,j] )
// One K=128 GEMM: A = [mean | xd] (bf16, swizzled LDS), B = [Wl ; Wr] (bf16
// register fragments, loaded once per block). Wave w owns rows w*16..w*16+15
// of each 64-row group; block covers 512 rows. C/D: col=lane&15,
// row=(lane>>4)*4+reg. In-place outb==xd safe (staged, synced, overwritten).
// HEAD: t2 restaged bf16 wave-locally into sH, K=64 MFMA GEMM, 16-lane
// shfl_xor reduce for the 64->2 contraction.
template<bool HEAD>
__global__ __launch_bounds__(256, 2)
void sage_mfma_kernel(const bf16* __restrict__ mean, const bf16* __restrict__ xd,
                      const float* __restrict__ Wl, const float* __restrict__ bl,
                      const float* __restrict__ Wr,
                      float* __restrict__ outf, bf16* __restrict__ outb,
                      const float* __restrict__ Wh1, const float* __restrict__ bh1,
                      const float* __restrict__ Wh2, const float* __restrict__ bh2,
                      float* __restrict__ logits, int n) {
    __shared__ __align__(16) short sA[64 * 128];              // 16 KB
    __shared__ __align__(16) short sH[HEAD ? 64 * 64 : 8];    // 8 KB (HEAD)
    int tid = threadIdx.x;
    int lane = tid & 63, w = tid >> 6;
    int lm = lane & 15, lq = lane >> 4;

    // --- weight fragments: once per block, held in registers ---
    bf16x8 wc[4][4];   // [col-tile][k-step]; ks 0,1 = Wl(k0=0,32), ks 2,3 = Wr
    bf16x8 wh[4][2];
    float blv[4], h1v[4], w2a[4], w2b[4];
#pragma unroll
    for (int ct = 0; ct < 4; ++ct) {
        int col = ct * 16 + lm;
        wc[ct][0] = load_bfrag(Wl, lq * 8, col);
        wc[ct][1] = load_bfrag(Wl, 32 + lq * 8, col);
        wc[ct][2] = load_bfrag(Wr, lq * 8, col);
        wc[ct][3] = load_bfrag(Wr, 32 + lq * 8, col);
        blv[ct] = bl[col];
        if (HEAD) {
            wh[ct][0] = load_bfrag(Wh1, lq * 8, col);
            wh[ct][1] = load_bfrag(Wh1, 32 + lq * 8, col);
            h1v[ct] = bh1[col];
            w2a[ct] = Wh2[col * 2 + 0];
            w2b[ct] = Wh2[col * 2 + 1];
        }
    }
    float b20 = 0.f, b21 = 0.f;
    if (HEAD) { b20 = bh2[0]; b21 = bh2[1]; }

    const bf16x8* mean8 = (const bf16x8*)mean;
    const bf16x8* xd8   = (const bf16x8*)xd;

    for (int g = 0; g < 8; ++g) {
        int row0 = blockIdx.x * 512 + g * 64;
        if (row0 >= n) break;
        __syncthreads();   // protect sA reuse (prev group's fragment reads done)
        // stage mean -> cols 0..63, xd -> cols 64..127 (16B granules, 2/thread each)
#pragma unroll
        for (int i = 0; i < 2; ++i) {
            int idx = tid + i * 256;             // 0..511
            int row = idx >> 3, c8 = idx & 7;    // 8x16B per 64-col row
            int grow = row0 + row;
            bf16x8 m, u;
#pragma unroll
            for (int j = 0; j < 8; ++j) { m[j] = 0; u[j] = 0; }
            if (grow < n) {
                m = mean8[(size_t)grow * 8 + c8];
                u = xd8[(size_t)grow * 8 + c8];
            }
            *(bf16x8*)((char*)sA + swzA(row, c8 * 16)) = m;
            *(bf16x8*)((char*)sA + swzA(row, 128 + c8 * 16)) = u;
        }
        __syncthreads();

        // --- compute: wave w owns rows w*16..w*16+15 ---
        int arow = w * 16 + lm;
        bf16x8 a0 = *(const bf16x8*)((char*)sA + swzA(arow, lq * 16));
        bf16x8 a1 = *(const bf16x8*)((char*)sA + swzA(arow, 64 + lq * 16));
        bf16x8 a2 = *(const bf16x8*)((char*)sA + swzA(arow, 128 + lq * 16));
        bf16x8 a3 = *(const bf16x8*)((char*)sA + swzA(arow, 192 + lq * 16));
#pragma unroll
        for (int ct = 0; ct < 4; ++ct) {
            f32x4 acc = {0.f, 0.f, 0.f, 0.f};
            acc = mfma16(a0, wc[ct][0], acc);
            acc = mfma16(a1, wc[ct][1], acc);
            acc = mfma16(a2, wc[ct][2], acc);
            acc = mfma16(a3, wc[ct][3], acc);
            int col = ct * 16 + lm;
#pragma unroll
            for (int r = 0; r < 4; ++r) {
                int lrow = w * 16 + lq * 4 + r;
                int grow = row0 + lrow;
                float v = fmaxf(acc[r] + blv[ct], 0.f);
                if (grow < n) {
                    if (outf) outf[(size_t)grow * 64 + col] = v;
                    if (outb) outb[(size_t)grow * 64 + col] = f2b(v);
                }
                if (HEAD)   // wave-local restage; same wave reads below
                    *(short*)((char*)sH + swzH(lrow, col * 2)) = (short)f2bb(v);
            }
        }
        if (HEAD) {
            bf16x8 h0 = *(const bf16x8*)((char*)sH + swzH(arow, lq * 16));
            bf16x8 h1 = *(const bf16x8*)((char*)sH + swzH(arow, 64 + lq * 16));
            float qa0 = 0.f, qa1 = 0.f, qa2 = 0.f, qa3 = 0.f;
            float qb0 = 0.f, qb1 = 0.f, qb2 = 0.f, qb3 = 0.f;
#pragma unroll
            for (int ct = 0; ct < 4; ++ct) {
                f32x4 acc = {0.f, 0.f, 0.f, 0.f};
                acc = mfma16(h0, wh[ct][0], acc);
                acc = mfma16(h1, wh[ct][1], acc);
                float hb = h1v[ct];
                float h_0 = fmaxf(acc[0] + hb, 0.f);
                float h_1 = fmaxf(acc[1] + hb, 0.f);
                float h_2 = fmaxf(acc[2] + hb, 0.f);
                float h_3 = fmaxf(acc[3] + hb, 0.f);
                qa0 += h_0 * w2a[ct]; qb0 += h_0 * w2b[ct];
                qa1 += h_1 * w2a[ct]; qb1 += h_1 * w2b[ct];
                qa2 += h_2 * w2a[ct]; qb2 += h_2 * w2b[ct];
                qa3 += h_3 * w2a[ct]; qb3 += h_3 * w2b[ct];
            }
#pragma unroll
            for (int m = 8; m; m >>= 1) {   // reduce over the 16-lane quad
                qa0 += __shfl_xor(qa0, m); qb0 += __shfl_xor(qb0, m);
                qa1 += __shfl_xor(qa1, m); qb1 += __shfl_xor(qb1, m);
                qa2 += __shfl_xor(qa2, m); qb2 += __shfl_xor(qb2, m);
                qa3 += __shfl_xor(qa3, m); qb3 += __shfl_xor(qb3, m);
            }
            int rowb = row0 + w * 16 + lq * 4;
            if (lm == 0) {
                if (rowb + 0 < n) { logits[(size_t)(rowb + 0) * 2 + 0] = qa0 + b20;
                                    logits[(size_t)(rowb + 0) * 2 + 1] = qb0 + b21; }
                if (rowb + 1 < n) { logits[(size_t)(rowb + 1) * 2 + 0] = qa1 + b20;
                                    logits[(size_t)(rowb + 1) * 2 + 1] = qb1 + b21; }
                if (rowb + 2 < n) { logits[(size_t)(rowb + 2) * 2 + 0] = qa2 + b20;
                                    logits[(size_t)(rowb + 2) * 2 + 1] = qb2 + b21; }
                if (rowb + 3 < n) { logits[(size_t)(rowb + 3) * 2 + 0] = qa3 + b20;
                                    logits[(size_t)(rowb + 3) * 2 + 1] = qb3 + b21; }
            }
        }
    }
}

// out[i,j] = sum_k x[i,k]*W[k,j] + b[j]   (x,W,b f32 -> out bf16), no relu
// (VALU version, used only for the small F=32 projection)
template<int F>
__global__ void proj_kernel(const float* __restrict__ x, const float* __restrict__ W,
                            const float* __restrict__ b, bf16* __restrict__ out, int n) {
    __shared__ float sW[F][64];
    __shared__ float sb[64];
    __shared__ float sx[16][F];
    int tid = threadIdx.x;
    for (int idx = tid; idx < F * 16; idx += 256)
        ((float4*)sW)[idx] = ((const float4*)W)[idx];
    if (tid < 64) sb[tid] = b[tid];
    int base = blockIdx.x * 64;
    int w = tid >> 6, j = tid & 63;
    int lw = w * 4;
    for (int g = 0; g < 4; ++g) {
        int row0 = base + g * 16;
        __syncthreads();
        for (int idx = tid; idx < 4 * F; idx += 256) {
            int rr = idx / (F / 4), c4 = idx - rr * (F / 4);
            int row = row0 + rr;
            float4 v = (row < n) ? ((const float4*)x)[(size_t)row * (F / 4) + c4]
                                 : make_float4(0.f, 0.f, 0.f, 0.f);
            *(float4*)&sx[rr][c4 * 4] = v;
        }
        __syncthreads();
        float a0 = sb[j], a1 = sb[j], a2 = sb[j], a3 = sb[j];
#pragma unroll 2
        for (int k = 0; k < F; k += 4) {
            float w0 = sW[k][j], w1 = sW[k + 1][j], w2 = sW[k + 2][j], w3 = sW[k + 3][j];
            float4 m0 = *(const float4*)&sx[lw + 0][k];
            float4 m1 = *(const float4*)&sx[lw + 1][k];
            float4 m2 = *(const float4*)&sx[lw + 2][k];
            float4 m3 = *(const float4*)&sx[lw + 3][k];
            a0 += m0.x * w0 + m0.y * w1 + m0.z * w2 + m0.w * w3;
            a1 += m1.x * w0 + m1.y * w1 + m1.z * w2 + m1.w * w3;
            a2 += m2.x * w0 + m2.y * w1 + m2.z * w2 + m2.w * w3;
            a3 += m3.x * w0 + m3.y * w1 + m3.z * w2 + m3.w * w3;
        }
        int r0 = row0 + lw;
        if (r0 + 0 < n) out[(size_t)(r0 + 0) * 64 + j] = f2b(a0);
        if (r0 + 1 < n) out[(size_t)(r0 + 1) * 64 + j] = f2b(a1);
        if (r0 + 2 < n) out[(size_t)(r0 + 2) * 64 + j] = f2b(a2);
        if (r0 + 3 < n) out[(size_t)(r0 + 3) * 64 + j] = f2b(a3);
    }
}

extern "C" void kernel_launch(void* const* d_in, const int* in_sizes, int n_in,
                              void* d_out, int out_size, void* d_ws, size_t ws_size,
                              hipStream_t stream) {
    const float* x_tx   = (const float*)d_in[0];
    const float* x_w    = (const float*)d_in[1];
    const int*   src_tw = (const int*)d_in[2];
    const int*   dst_tw = (const int*)d_in[3];
    const int*   src_wt = (const int*)d_in[4];
    const int*   dst_wt = (const int*)d_in[5];
    const float* Win_tx = (const float*)d_in[6];
    const float* bin_tx = (const float*)d_in[7];
    const float* Win_w  = (const float*)d_in[8];
    const float* bin_w  = (const float*)d_in[9];
    const float* Wl1_tw = (const float*)d_in[10];
    const float* bl1_tw = (const float*)d_in[11];
    const float* Wr1_tw = (const float*)d_in[12];
    const float* Wl1_wt = (const float*)d_in[13];
    const float* bl1_wt = (const float*)d_in[14];
    const float* Wr1_wt = (const float*)d_in[15];
    const float* Wl2_tw = (const float*)d_in[16];
    const float* bl2_tw = (const float*)d_in[17];
    const float* Wr2_tw = (const float*)d_in[18];
    const float* Wl2_wt = (const float*)d_in[19];
    const float* bl2_wt = (const float*)d_in[20];
    const float* Wr2_wt = (const float*)d_in[21];
    const float* Wh1    = (const float*)d_in[22];
    const float* bh1    = (const float*)d_in[23];
    const float* Wh2    = (const float*)d_in[24];
    const float* bh2    = (const float*)d_in[25];

    const int n_tx  = in_sizes[0] / 64;
    const int n_w   = in_sizes[1] / 32;
    const int ne_tw = in_sizes[2];
    const int ne_wt = in_sizes[4];

    // ---- workspace layout (~351 MB) ----
    bf16* mean_tx = (bf16*)d_ws;                          // n_tx*64 bf16 (128 MB)
    bf16* mean_w  = mean_tx + (size_t)n_tx * 64;          // n_w *64 bf16 ( 32 MB)
    bf16* A       = mean_w + (size_t)n_w * 64;            // n_tx*64 bf16: h_tx->t1 (in-place)
    bf16* B       = A + (size_t)n_tx * 64;                // n_w *64 bf16: h_w ->w1 (in-place)
    int*  deg_w   = (int*)(B + (size_t)n_w * 64);         // n_w
    int*  deg_tx  = deg_w + n_w;                          // n_tx
    int*  rp_w    = deg_tx + n_tx;                        // n_w
    int*  rp_tx   = rp_w + n_w;                           // n_tx
    int*  cur_w   = rp_tx + n_tx;                         // n_w  (excl scratch, then cursor)
    int*  cur_tx  = cur_w + n_w;                          // n_tx
    int*  col_tw  = cur_tx + n_tx;                        // ne_tw
    int*  col_wt  = col_tw + ne_tw;                       // ne_wt
    int*  part_w  = col_wt + ne_wt;                       // <=4096
    int*  part_tx = part_w + 4096;                        // <=4096

    float* out_logits = (float*)d_out;
    float* out_t2 = out_logits + (size_t)n_tx * 2;
    float* out_w2 = out_t2 + (size_t)n_tx * 64;

    dim3 blk(256);
    int grid_proj_tx = (n_tx + 511) / 512;
    int grid_proj_w  = (n_w + 63) / 64;
    int grid_sage_tx = (n_tx + 511) / 512;
    int grid_sage_w  = (n_w + 511) / 512;
    int grid_e_tw    = (ne_tw + 255) / 256;
    int grid_e_wt    = (ne_wt + 255) / 256;
    int grid_g_tx    = (n_tx + 31) / 32;
    int grid_g_w     = (n_w + 31) / 32;
    int np_w  = (n_w + 1023) / 1024;
    int np_tx = (n_tx + 1023) / 1024;

    // ---- CSR build (graph static: reused by conv1 AND conv2) ----
    hipMemsetAsync(deg_w, 0, (size_t)n_w * sizeof(int), stream);
    hipMemsetAsync(deg_tx, 0, (size_t)n_tx * sizeof(int), stream);
    count_int_kernel<<<grid_e_tw, blk, 0, stream>>>(dst_tw, deg_w, ne_tw);
    count_int_kernel<<<grid_e_wt, blk, 0, stream>>>(dst_wt, deg_tx, ne_wt);
    scan1_kernel<<<np_w, blk, 0, stream>>>(deg_w, cur_w, part_w, n_w);
    scan2_kernel<<<1, blk, 0, stream>>>(part_w, np_w);
    scan3_kernel<<<(n_w + 255) / 256, blk, 0, stream>>>(cur_w, part_w, rp_w, cur_w, n_w);
    scan1_kernel<<<np_tx, blk, 0, stream>>>(deg_tx, cur_tx, part_tx, n_tx);
    scan2_kernel<<<1, blk, 0, stream>>>(part_tx, np_tx);
    scan3_kernel<<<(n_tx + 255) / 256, blk, 0, stream>>>(cur_tx, part_tx, rp_tx, cur_tx, n_tx);
    scatter_kernel<<<grid_e_tw, blk, 0, stream>>>(src_tw, dst_tw, cur_w, col_tw, ne_tw);
    scatter_kernel<<<grid_e_wt, blk, 0, stream>>>(src_wt, dst_wt, cur_tx, col_wt, ne_wt);

    // ---- input projections ----
    proj64_mfma_kernel<<<grid_proj_tx, blk, 0, stream>>>(x_tx, Win_tx, bin_tx, A, n_tx);
    proj_kernel<32><<<grid_proj_w, blk, 0, stream>>>(x_w, Win_w, bin_w, B, n_w);

    // ---- conv1: gather both means (from h_tx=A, h_w=B), then both epilogues ----
    gather_mean_kernel<<<grid_g_w, blk, 0, stream>>>(A, rp_w, deg_w, col_tw, mean_w, n_w);
    gather_mean_kernel<<<grid_g_tx, blk, 0, stream>>>(B, rp_tx, deg_tx, col_wt, mean_tx, n_tx);
    sage_mfma_kernel<false><<<grid_sage_w, blk, 0, stream>>>(
        mean_w, B, Wl1_tw, bl1_tw, Wr1_tw,
        nullptr, B, nullptr, nullptr, nullptr, nullptr, nullptr, n_w);    // w1 (in-place B)
    sage_mfma_kernel<false><<<grid_sage_tx, blk, 0, stream>>>(
        mean_tx, A, Wl1_wt, bl1_wt, Wr1_wt,
        nullptr, A, nullptr, nullptr, nullptr, nullptr, nullptr, n_tx);   // t1 (in-place A)

    // ---- conv2: gather from t1=A, w1=B, then both epilogues ----
    gather_mean_kernel<<<grid_g_w, blk, 0, stream>>>(A, rp_w, deg_w, col_tw, mean_w, n_w);
    gather_mean_kernel<<<grid_g_tx, blk, 0, stream>>>(B, rp_tx, deg_tx, col_wt, mean_tx, n_tx);
    sage_mfma_kernel<false><<<grid_sage_w, blk, 0, stream>>>(
        mean_w, B, Wl2_tw, bl2_tw, Wr2_tw,
        out_w2, nullptr, nullptr, nullptr, nullptr, nullptr, nullptr, n_w);   // w2 -> f32 out
    sage_mfma_kernel<true><<<grid_sage_tx, blk, 0, stream>>>(
        mean_tx, A, Wl2_wt, bl2_wt, Wr2_wt,
        out_t2, nullptr, Wh1, bh1, Wh2, bh2, out_logits, n_tx);               // t2 + logits
}